// Round 1
// baseline (75804.639 us; speedup 1.0000x reference)
//
#include <hip/hip_runtime.h>

#define NB 256
#define NT 256

// B=32, S=24, T=48, all hidden dims 512, gate dim 2048.
// Block w owns hidden units {2w, 2w+1} of scene/L0/L1 cells.
// Local gate-row index r in [0,8): gate g = r>>1 (i,f,g,o), unit uu = r&1.
// Global gate row = (r>>1)*512 + 2*w + (r&1).

struct SMem {
  float A[3][8][512];      // persistent: W0_hh, W1_ih, W1_hh rows (48KB)
  float Bh[32 * 256];      // skewed h staging tile (32KB): half of [32][512]
  float Cw[8 * 512];       // scratch weight rows (16KB)
  float P[8][32][2];       // dot partials (rows x batch x k-half)
  float G[8][32];          // combined gates
  float X[32][8];          // x_t (5 used)
  float own_c0[2][32], own_h0[2][32];
  float own_c1[2][32], own_h1[2][32];
  float own_csc[2][32];
  int   lens[32];
  int   Lmax;
  float outred[4];
};

__device__ __forceinline__ float sigm(float x) { return 1.0f / (1.0f + expf(-x)); }

extern "C" __global__ void __launch_bounds__(NT, 1)
rnn_decoder_kernel(const float* __restrict__ enc, const float* __restrict__ sketch,
                   const int* __restrict__ slen,
                   const float* __restrict__ Wsc_ih, const float* __restrict__ Wsc_hh,
                   const float* __restrict__ bsc,
                   const float* __restrict__ W0ih, const float* __restrict__ W0hh,
                   const float* __restrict__ b0,
                   const float* __restrict__ W1ih, const float* __restrict__ W1hh,
                   const float* __restrict__ b1,
                   const float* __restrict__ Wout, const float* __restrict__ bout,
                   float* __restrict__ out, float* __restrict__ ws)
{
  extern __shared__ char smraw[];
  SMem* sm = (SMem*)smraw;
  const int tid = threadIdx.x;
  const int w = blockIdx.x;

  unsigned* bcnt = (unsigned*)ws;        // barrier counter
  unsigned* bgen = bcnt + 32;            // barrier generation (128B apart)
  float* h0T = ws + 64;                  // [2][32][512]
  float* h1T = h0T + 2 * 16384;          // [2][32][512]
  float* sHg = h1T + 2 * 16384;          // [2][32][512]

  const int rp = tid >> 6;               // row-pair 0..3 (rows 2rp, 2rp+1)
  const int bd = (tid >> 1) & 31;        // dot batch
  const int ks = tid & 1;                // k-interleave selector
  const int rc = tid >> 5;               // combine row 0..7
  const int bc = tid & 31;               // combine batch

  auto grow = [&](int r) { return ((r >> 1) * 512) + 2 * w + (r & 1); };

  // ---------------- global barrier ----------------
  auto gbar = [&]() {
    __builtin_amdgcn_fence(__ATOMIC_RELEASE, "agent");
    __syncthreads();
    if (tid == 0) {
      unsigned g = __hip_atomic_load(bgen, __ATOMIC_RELAXED, __HIP_MEMORY_SCOPE_AGENT);
      unsigned a = __hip_atomic_fetch_add(bcnt, 1u, __ATOMIC_RELAXED, __HIP_MEMORY_SCOPE_AGENT);
      if (a == (unsigned)(NB - 1)) {
        __hip_atomic_store(bcnt, 0u, __ATOMIC_RELAXED, __HIP_MEMORY_SCOPE_AGENT);
        __hip_atomic_store(bgen, g + 1u, __ATOMIC_RELEASE, __HIP_MEMORY_SCOPE_AGENT);
      } else {
        int spins = 0;
        while (__hip_atomic_load(bgen, __ATOMIC_RELAXED, __HIP_MEMORY_SCOPE_AGENT) == g) {
          __builtin_amdgcn_s_sleep(2);
          if (++spins > 8000) break;   // safety bailout: garbage > hang
        }
      }
    }
    __syncthreads();
    __builtin_amdgcn_fence(__ATOMIC_ACQUIRE, "agent");
  };

  // -------- stage half hh of src[32][512] into skewed Bh --------
  auto stage = [&](const float* src, int hh) {
    const float4* s4 = (const float4*)src;
    float4* d4 = (float4*)sm->Bh;
#pragma unroll
    for (int it = 0; it < 8; ++it) {
      int g = tid + it * 256;            // 0..2047 chunk id
      int b = g >> 6, c = g & 63;
      float4 v = s4[b * 128 + hh * 64 + c];
      int pos = (c & 32) | ((c + b) & 31);   // bank skew
      d4[b * 64 + pos] = v;
    }
  };

  auto dot_half = [&](const float* Wbase, int hh, float& a0, float& a1) {
    const float4* B4 = (const float4*)sm->Bh;
    const float4* W4 = (const float4*)Wbase;
#pragma unroll
    for (int j = 0; j < 32; ++j) {
      int c = 2 * j + ks;
      int pos = (c & 32) | ((c + bd) & 31);
      float4 h = B4[bd * 64 + pos];
      float4 u = W4[(2 * rp) * 128 + hh * 64 + c];
      float4 v = W4[(2 * rp + 1) * 128 + hh * 64 + c];
      a0 += h.x * u.x + h.y * u.y + h.z * u.z + h.w * u.w;
      a1 += h.x * v.x + h.y * v.y + h.z * v.z + h.w * v.w;
    }
  };

  // full K=512 dot of Wbase(8x512) with src(32x512): accumulates a0,a1
  auto dot512 = [&](const float* Wbase, const float* src, float& a0, float& a1) {
    __syncthreads();                     // Bh free
    stage(src, 0); __syncthreads();
    dot_half(Wbase, 0, a0, a1);
    __syncthreads();
    stage(src, 1); __syncthreads();
    dot_half(Wbase, 1, a0, a1);
  };

  // ---------------- init: persistent weights ----------------
  {
    const float* srcs[3] = {W0hh, W1ih, W1hh};
    for (int m = 0; m < 3; ++m) {
      float4* A4 = (float4*)&sm->A[m][0][0];
#pragma unroll
      for (int it = 0; it < 4; ++it) {
        int e = tid + it * 256; int r = e >> 7, c = e & 127;
        A4[r * 128 + c] = *(const float4*)(srcs[m] + grow(r) * 512 + 4 * c);
      }
    }
  }
  const int gr = grow(rc);
  const float b0r = b0[gr], b1r = b1[gr], bscr = bsc[gr];
  const float wx0 = W0ih[gr * 517 + 512], wx1 = W0ih[gr * 517 + 513],
              wx2 = W0ih[gr * 517 + 514], wx3 = W0ih[gr * 517 + 515],
              wx4 = W0ih[gr * 517 + 516];
  const int oo = w % 5, bo = w / 5;      // out role (w < 160)
  float4 wo4 = make_float4(0.f, 0.f, 0.f, 0.f);
  float bor = 0.f;
  if (w < 160) {
    bor = bout[oo];
    if (tid < 128) wo4 = *(const float4*)(Wout + oo * 512 + 4 * tid);
  }
  if (tid < 64) { sm->own_csc[tid >> 5][tid & 31] = 0.f; }

  // e0 = bsc + enc @ Wsc_ih[:, :512].T   (per (rc,bc) register)
  float e0reg;
  {
    float4* Cw4 = (float4*)sm->Cw;
#pragma unroll
    for (int it = 0; it < 4; ++it) {
      int e = tid + it * 256; int r = e >> 7, c = e & 127;
      Cw4[r * 128 + c] = *(const float4*)(Wsc_ih + grow(r) * 1024 + 4 * c);
    }
    float a0 = 0.f, a1 = 0.f;
    dot512(sm->Cw, enc, a0, a1);
    sm->P[2 * rp][bd][ks] = a0; sm->P[2 * rp + 1][bd][ks] = a1;
    __syncthreads();
    e0reg = bscr + sm->P[rc][bc][0] + sm->P[rc][bc][1];
    __syncthreads();
  }

  float s0reg = 0.f;

  for (int s = 0; s < 24; ++s) {
    // ================= scene phase =================
    if (tid < 32) sm->lens[tid] = slen[tid * 24 + s];
    __syncthreads();
    if (tid == 0) {
      int L = 0;
      for (int b2 = 0; b2 < 32; ++b2) L = max(L, sm->lens[b2]);
      sm->Lmax = L;
    }
    float gsc;
    if (s > 0) {
      float a0 = 0.f, a1 = 0.f;
      {
        float4* Cw4 = (float4*)sm->Cw;   // Wsc_ih[:, 512:1024] (prev_tok part)
#pragma unroll
        for (int it = 0; it < 4; ++it) {
          int e = tid + it * 256; int r = e >> 7, c = e & 127;
          Cw4[r * 128 + c] = *(const float4*)(Wsc_ih + grow(r) * 1024 + 512 + 4 * c);
        }
      }
      dot512(sm->Cw, h1T /*buf0 = final h1 of prev stroke*/, a0, a1);
      __syncthreads();
      {
        float4* Cw4 = (float4*)sm->Cw;   // Wsc_hh
#pragma unroll
        for (int it = 0; it < 4; ++it) {
          int e = tid + it * 256; int r = e >> 7, c = e & 127;
          Cw4[r * 128 + c] = *(const float4*)(Wsc_hh + grow(r) * 512 + 4 * c);
        }
      }
      dot512(sm->Cw, sHg + ((s - 1) & 1) * 16384, a0, a1);
      sm->P[2 * rp][bd][ks] = a0; sm->P[2 * rp + 1][bd][ks] = a1;
      __syncthreads();
      gsc = e0reg + sm->P[rc][bc][0] + sm->P[rc][bc][1];
    } else {
      gsc = e0reg;
    }
    sm->G[rc][bc] = gsc;
    __syncthreads();
    if (tid < 64) {
      int uu = tid >> 5, bb = tid & 31;
      float gi = sm->G[0 + uu][bb], gf = sm->G[2 + uu][bb];
      float gg = sm->G[4 + uu][bb], go = sm->G[6 + uu][bb];
      float c = sigm(gf) * sm->own_csc[uu][bb] + sigm(gi) * tanhf(gg);
      float h = sigm(go) * tanhf(c);
      sm->own_csc[uu][bb] = c;
      sHg[(s & 1) * 16384 + bb * 512 + 2 * w + uu] = h;
      sm->own_c0[uu][bb] = 0.f; sm->own_h0[uu][bb] = 0.f;
      sm->own_c1[uu][bb] = 0.f; sm->own_h1[uu][bb] = 0.f;
    }
    gbar();

    // ================= time steps =================
    for (int t = 0; t <= 48; ++t) {
      const int p = t & 1;

      // ---------- L0 phase ----------
      if (tid < 32) {
        int b = tid;
        float xv[5];
        if (t == 0) {
          if (s == 0) { xv[0] = 0.f; xv[1] = 0.f; xv[2] = 1.f; xv[3] = 0.f; xv[4] = 0.f; }
          else {
            int lp = slen[b * 24 + (s - 1)];
            int last = min(max(lp - 1, 0), 47);
            const float* q = sketch + ((b * 24 + (s - 1)) * 48 + last) * 5;
            for (int j2 = 0; j2 < 5; ++j2) xv[j2] = q[j2];
          }
        } else {
          const float* q = sketch + ((b * 24 + s) * 48 + (t - 1)) * 5;
          for (int j2 = 0; j2 < 5; ++j2) xv[j2] = q[j2];
        }
        for (int j2 = 0; j2 < 5; ++j2) sm->X[b][j2] = xv[j2];
      }
      float4 hv4 = make_float4(0.f, 0.f, 0.f, 0.f);   // early out-dot load
      if (w < 160 && t > 0 && tid < 128)
        hv4 = *(const float4*)(h1T + ((t - 1) & 1) * 16384 + bo * 512 + 4 * tid);

      float a0 = 0.f, a1 = 0.f;
      if (t == 0) {
        // Cw <- W0_ih[:, :512] (row stride 517 -> scalar loads)
#pragma unroll
        for (int it = 0; it < 16; ++it) {
          int e = tid + it * 256; int r = e >> 9, k = e & 511;
          sm->Cw[r * 512 + k] = W0ih[grow(r) * 517 + k];
        }
        dot512(sm->Cw, sHg + (s & 1) * 16384, a0, a1);
      } else {
        dot512((const float*)sm->A[0], h0T + (1 - p) * 16384, a0, a1);
      }
      sm->P[2 * rp][bd][ks] = a0; sm->P[2 * rp + 1][bd][ks] = a1;
      __syncthreads();
      {
        float raw = sm->P[rc][bc][0] + sm->P[rc][bc][1];
        float xdot = wx0 * sm->X[bc][0] + wx1 * sm->X[bc][1] + wx2 * sm->X[bc][2]
                   + wx3 * sm->X[bc][3] + wx4 * sm->X[bc][4];
        float g0;
        if (t == 0) { s0reg = raw + b0r; g0 = s0reg + xdot; }
        else        { g0 = s0reg + xdot + raw; }
        sm->G[rc][bc] = g0;
      }
      __syncthreads();
      if (tid < 64) {
        int uu = tid >> 5, bb = tid & 31;
        if (t <= sm->lens[bb]) {
          float gi = sm->G[0 + uu][bb], gf = sm->G[2 + uu][bb];
          float gg = sm->G[4 + uu][bb], go = sm->G[6 + uu][bb];
          float c = sigm(gf) * sm->own_c0[uu][bb] + sigm(gi) * tanhf(gg);
          sm->own_c0[uu][bb] = c;
          sm->own_h0[uu][bb] = sigm(go) * tanhf(c);
        }
        h0T[p * 16384 + bb * 512 + 2 * w + uu] = sm->own_h0[uu][bb];
      }
      // fused output: out(t-1) from h1(t-1)
      float part = 0.f;
      if (w < 160 && t > 0 && tid < 128)
        part = hv4.x * wo4.x + hv4.y * wo4.y + hv4.z * wo4.z + hv4.w * wo4.w;
#pragma unroll
      for (int off = 1; off < 64; off <<= 1) part += __shfl_xor(part, off, 64);
      if ((tid & 63) == 0) sm->outred[tid >> 6] = part;
      __syncthreads();
      if (w < 160 && t > 0 && tid == 0) {
        float dv = sm->outred[0] + sm->outred[1];
        int tt = t - 1;
        float val = 0.f;
        if (tt < sm->Lmax) val = (tt > sm->lens[bo]) ? bor : (dv + bor);
        out[((bo * 24 + s) * 48 + tt) * 5 + oo] = val;
      }
      gbar();

      // ---------- L1 phase ----------
      float c0a = 0.f, c1a = 0.f;
      dot512((const float*)sm->A[1], h0T + p * 16384, c0a, c1a);
      if (t > 0) dot512((const float*)sm->A[2], h1T + (1 - p) * 16384, c0a, c1a);
      sm->P[2 * rp][bd][ks] = c0a; sm->P[2 * rp + 1][bd][ks] = c1a;
      __syncthreads();
      {
        float g1 = b1r + sm->P[rc][bc][0] + sm->P[rc][bc][1];
        sm->G[rc][bc] = g1;
      }
      __syncthreads();
      if (tid < 64) {
        int uu = tid >> 5, bb = tid & 31;
        if (t <= sm->lens[bb]) {
          float gi = sm->G[0 + uu][bb], gf = sm->G[2 + uu][bb];
          float gg = sm->G[4 + uu][bb], go = sm->G[6 + uu][bb];
          float c = sigm(gf) * sm->own_c1[uu][bb] + sigm(gi) * tanhf(gg);
          sm->own_c1[uu][bb] = c;
          sm->own_h1[uu][bb] = sigm(go) * tanhf(c);
        }
        h1T[p * 16384 + bb * 512 + 2 * w + uu] = sm->own_h1[uu][bb];
      }
      gbar();
    }
  }
}

extern "C" void kernel_launch(void* const* d_in, const int* in_sizes, int n_in,
                              void* d_out, int out_size, void* d_ws, size_t ws_size,
                              hipStream_t stream) {
  (void)in_sizes; (void)n_in; (void)out_size; (void)ws_size;
  hipFuncSetAttribute((const void*)rnn_decoder_kernel,
                      hipFuncAttributeMaxDynamicSharedMemorySize, (int)sizeof(SMem));
  // reset barrier state (ws is poisoned once; counters must start at 0)
  hipMemsetAsync(d_ws, 0, 256, stream);
  rnn_decoder_kernel<<<dim3(NB), dim3(NT), sizeof(SMem), stream>>>(
      (const float*)d_in[0],   // enc_features
      (const float*)d_in[1],   // vector_sketch
      (const int*)d_in[3],     // batch_stroke_len
      (const float*)d_in[4],   // W_sc_ih
      (const float*)d_in[5],   // W_sc_hh
      (const float*)d_in[6],   // b_sc
      (const float*)d_in[7],   // W0_ih
      (const float*)d_in[8],   // W0_hh
      (const float*)d_in[9],   // b0
      (const float*)d_in[10],  // W1_ih
      (const float*)d_in[11],  // W1_hh
      (const float*)d_in[12],  // b1
      (const float*)d_in[13],  // W_out
      (const float*)d_in[14],  // b_out
      (float*)d_out, (float*)d_ws);
}

// Round 2
// 58189.319 us; speedup vs baseline: 1.3027x; 1.3027x over previous
//
#include <hip/hip_runtime.h>

#define NB 256
#define NT 256
#define AGT __HIP_MEMORY_SCOPE_AGENT

// B=32, S=24, T=48, hidden 512, gate dim 2048.
// Block w owns hidden units {2w,2w+1}; local gate-row r in [0,8):
// global gate row = (r>>1)*512 + 2w + (r&1)  (gate g=r>>1 in i,f,g,o; unit=r&1).
//
// Fused iteration k (k=0..48): computes h1(k)=L1cell(h0(k),h1(k-1)) and
// h0(k+1)=L0cell(h0(k),x_{k+1}) -> ONE global barrier per k. 51 barriers/stroke.
//
// Dot mapping: 8 half-wave groups x 32 k-lanes; each thread tiles 4 rows x 8
// batches over a 16-float K slice (lane-consecutive float4 -> conflict-free),
// K-partials folded across 32 lanes with a 31-shuffle butterfly (lane l ends
// holding output (r=l>>3, b=l&7) of its group).

struct __align__(16) SMem {
  float A[3][8][512];      // persistent W0hh, W1ih, W1hh rows (48KB)
  float Bh[32 * 512];      // staged h tile (64KB), linear, conflict-free
  float Cw[8 * 512];       // streamed weight rows (16KB)
  float G0[8][32];         // raw L0 recurrent dot
  float G1[8][32];         // raw L1 dot
  float e0v[8][32];        // raw enc@Wsc_ih[:, :512] (per session)
  float s0v[8][32];        // raw sh2@W0ih[:, :512] (per stroke)
  float X[32][8];          // x_t
  float outred[4];
  int   lens[32];
  int   Lmax;
};

__device__ __forceinline__ float sigm(float x) { return 1.0f / (1.0f + expf(-x)); }

#define DOT8x32(WPTR, ACC) do { \
  const float4* B4_ = (const float4*)sm->Bh; \
  const float4* W4_ = (const float4*)(WPTR); \
  _Pragma("unroll") \
  for (int i_ = 0; i_ < 4; ++i_) { \
    const int kf_ = kl + 32 * i_; \
    float4 w0_ = W4_[(rg*4+0)*128 + kf_]; \
    float4 w1_ = W4_[(rg*4+1)*128 + kf_]; \
    float4 w2_ = W4_[(rg*4+2)*128 + kf_]; \
    float4 w3_ = W4_[(rg*4+3)*128 + kf_]; \
    _Pragma("unroll") \
    for (int b_ = 0; b_ < 8; ++b_) { \
      float4 h_ = B4_[(bg*8+b_)*128 + kf_]; \
      ACC[0*8+b_] += w0_.x*h_.x + w0_.y*h_.y + w0_.z*h_.z + w0_.w*h_.w; \
      ACC[1*8+b_] += w1_.x*h_.x + w1_.y*h_.y + w1_.z*h_.z + w1_.w*h_.w; \
      ACC[2*8+b_] += w2_.x*h_.x + w2_.y*h_.y + w2_.z*h_.z + w2_.w*h_.w; \
      ACC[3*8+b_] += w3_.x*h_.x + w3_.y*h_.y + w3_.z*h_.z + w3_.w*h_.w; \
    } \
  } \
} while (0)

// butterfly fold: 32 arrays x 32 lanes -> lane l holds full sum of array l.
#define REDUCE32(ACC, OUTV) do { \
  _Pragma("unroll") \
  for (int lvl_ = 0; lvl_ < 5; ++lvl_) { \
    const int mk_ = 1 << lvl_; \
    const int hc_ = 16 >> lvl_; \
    const bool hi_ = (lane >> lvl_) & 1; \
    _Pragma("unroll") \
    for (int i_ = 0; i_ < hc_; ++i_) { \
      float keep_ = hi_ ? ACC[2*i_+1] : ACC[2*i_]; \
      float send_ = hi_ ? ACC[2*i_]   : ACC[2*i_+1]; \
      ACC[i_] = keep_ + __shfl_xor(send_, mk_, 64); \
    } \
  } \
  OUTV = ACC[0]; \
} while (0)

extern "C" __global__ void __launch_bounds__(NT, 1)
rnn_decoder_kernel(const float* __restrict__ enc, const float* __restrict__ sketch,
                   const int* __restrict__ slen,
                   const float* __restrict__ Wsc_ih, const float* __restrict__ Wsc_hh,
                   const float* __restrict__ bsc,
                   const float* __restrict__ W0ih, const float* __restrict__ W0hh,
                   const float* __restrict__ b0,
                   const float* __restrict__ W1ih, const float* __restrict__ W1hh,
                   const float* __restrict__ b1,
                   const float* __restrict__ Wout, const float* __restrict__ bout,
                   float* __restrict__ out, float* __restrict__ ws)
{
  extern __shared__ char smraw[];
  SMem* sm = (SMem*)smraw;
  const int tid = threadIdx.x;
  const int w = blockIdx.x;
  const int lane = tid & 63;
  const int w4 = tid >> 6;
  const int grp = w4 * 2 + (lane >> 5);   // 0..7
  const int rg = grp & 1;                  // row-group (rows rg*4..rg*4+3)
  const int bg = grp >> 1;                 // batch-group (batches bg*8..bg*8+7)
  const int kl = lane & 31;                // k-lane
  const int my_r = rg * 4 + (kl >> 3);     // final-lane output row (0..7)
  const int my_b = bg * 8 + (kl & 7);      // final-lane output batch (0..31)
  const int uu = tid >> 5, bb = tid & 31;  // cell-math role (valid for tid<64)

  unsigned* flagsU = (unsigned*)ws;        // flags[w] at flagsU[w*32] (128B apart)
  unsigned* genU = flagsU + 8192;          // generation word (own line)
  float* hbase = ws + 8256;                // 128B-aligned data region
  float* h0T = hbase;                      // [2][32][512]
  float* h1T = hbase + 32768;              // [2][32][512]
  float* sHg = hbase + 65536;              // [2][32][512]

  auto grow = [&](int r) { return ((r >> 1) * 512) + 2 * w + (r & 1); };

  unsigned barid = 0;
  auto gbar = [&]() {
    ++barid;
    __builtin_amdgcn_fence(__ATOMIC_RELEASE, "agent");
    __syncthreads();
    if (w == 0) {
      if (tid < 64) {
        if (tid == 0) __hip_atomic_store(&flagsU[0], barid, __ATOMIC_RELEASE, AGT);
        int spins = 0;
        for (;;) {
          unsigned a0 = __hip_atomic_load(&flagsU[(unsigned)(tid)       * 32], __ATOMIC_RELAXED, AGT);
          unsigned a1 = __hip_atomic_load(&flagsU[(unsigned)(tid + 64)  * 32], __ATOMIC_RELAXED, AGT);
          unsigned a2 = __hip_atomic_load(&flagsU[(unsigned)(tid + 128) * 32], __ATOMIC_RELAXED, AGT);
          unsigned a3 = __hip_atomic_load(&flagsU[(unsigned)(tid + 192) * 32], __ATOMIC_RELAXED, AGT);
          bool ok = (a0 >= barid) & (a1 >= barid) & (a2 >= barid) & (a3 >= barid);
          if (__all(ok)) break;
          __builtin_amdgcn_s_sleep(1);
          if (++spins > 100000) break;   // bailout: garbage > hang
        }
        __builtin_amdgcn_fence(__ATOMIC_ACQUIRE, "agent");
        if (tid == 0) __hip_atomic_store(genU, barid, __ATOMIC_RELEASE, AGT);
      }
      __syncthreads();
    } else {
      if (tid == 0) {
        __hip_atomic_store(&flagsU[(unsigned)w * 32], barid, __ATOMIC_RELEASE, AGT);
        int spins = 0;
        while (__hip_atomic_load(genU, __ATOMIC_ACQUIRE, AGT) < barid) {
          __builtin_amdgcn_s_sleep(2);
          if (++spins > 100000) break;
        }
      }
      __syncthreads();
    }
    __builtin_amdgcn_fence(__ATOMIC_ACQUIRE, "agent");
  };

  auto stageF = [&](const float* src) {      // full [32][512] -> Bh, linear
    const float4* s4 = (const float4*)src;
    float4* d4 = (float4*)sm->Bh;
#pragma unroll
    for (int i = 0; i < 16; ++i) d4[tid + i * 256] = s4[tid + i * 256];
  };

  auto loadCw4 = [&](const float* src, int rowStride, int colOff) {
    float4* C4 = (float4*)sm->Cw;
#pragma unroll
    for (int i = 0; i < 4; ++i) {
      int e = tid + i * 256, r = e >> 7, c = e & 127;
      C4[r * 128 + c] = *(const float4*)(src + grow(r) * rowStride + colOff + 4 * c);
    }
  };

  // ---------------- init ----------------
  {
    const float* srcs[3] = {W0hh, W1ih, W1hh};
#pragma unroll
    for (int m = 0; m < 3; ++m) {
      float4* A4 = (float4*)&sm->A[m][0][0];
#pragma unroll
      for (int i = 0; i < 4; ++i) {
        int e = tid + i * 256, r = e >> 7, c = e & 127;
        A4[r * 128 + c] = *(const float4*)(srcs[m] + grow(r) * 512 + 4 * c);
      }
    }
  }
  float cb0[4] = {0,0,0,0}, cb1[4] = {0,0,0,0}, cbsc[4] = {0,0,0,0};
  float cwx[4][5] = {};
  if (tid < 64) {
#pragma unroll
    for (int gi = 0; gi < 4; ++gi) {
      int gr = grow(gi * 2 + uu);
      cb0[gi] = b0[gr]; cb1[gi] = b1[gr]; cbsc[gi] = bsc[gr];
#pragma unroll
      for (int j = 0; j < 5; ++j) cwx[gi][j] = W0ih[gr * 517 + 512 + j];
    }
  }
  const int oo = w % 5, bo = w / 5;          // out role (w < 160)
  float4 wo4 = make_float4(0.f, 0.f, 0.f, 0.f);
  float bor = 0.f;
  if (w < 160) {
    bor = bout[oo];
    if (tid < 128) wo4 = *(const float4*)(Wout + oo * 512 + 4 * tid);
  }

  // e0v = raw enc @ Wsc_ih[:, :512].T
  stageF(enc);
  loadCw4(Wsc_ih, 1024, 0);
  __syncthreads();
  {
    float acc[32];
#pragma unroll
    for (int i = 0; i < 32; ++i) acc[i] = 0.f;
    DOT8x32(sm->Cw, acc);
    float r;
    REDUCE32(acc, r);
    sm->e0v[my_r][my_b] = r;
  }

  float o_csc = 0.f, o_c0 = 0.f, o_h0 = 0.f, o_c1 = 0.f, o_h1 = 0.f;

  for (int s = 0; s < 24; ++s) {
    // ================= scene phase =================
    if (tid < 32) sm->lens[tid] = slen[tid * 24 + s];
    __syncthreads();
    if (tid == 0) {
      int L = 0;
      for (int b2 = 0; b2 < 32; ++b2) L = max(L, sm->lens[b2]);
      sm->Lmax = L;
    }
    if (s > 0) {
      stageF(h1T);                               // h1 final (parity 0)
      loadCw4(Wsc_ih, 1024, 512);                // prev_tok part
      __syncthreads();
      float acc[32];
#pragma unroll
      for (int i = 0; i < 32; ++i) acc[i] = 0.f;
      DOT8x32(sm->Cw, acc);
      __syncthreads();
      stageF(sHg + ((s - 1) & 1) * 16384);
      loadCw4(Wsc_hh, 512, 0);
      __syncthreads();
      DOT8x32(sm->Cw, acc);
      float r;
      REDUCE32(acc, r);
      sm->G0[my_r][my_b] = r;
    }
    __syncthreads();
    if (tid < 64) {
      float g[4];
#pragma unroll
      for (int gi = 0; gi < 4; ++gi)
        g[gi] = sm->e0v[gi*2+uu][bb] + cbsc[gi] + (s > 0 ? sm->G0[gi*2+uu][bb] : 0.f);
      float c = sigm(g[1]) * o_csc + sigm(g[0]) * tanhf(g[2]);
      float h = sigm(g[3]) * tanhf(c);
      o_csc = c;
      sHg[(s & 1) * 16384 + bb * 512 + 2 * w + uu] = h;
      o_c0 = o_h0 = o_c1 = o_h1 = 0.f;
    }
    gbar();

    // ================= t0 pre-step: h0(0) =================
    stageF(sHg + (s & 1) * 16384);
    {
#pragma unroll
      for (int i = 0; i < 16; ++i) {             // W0ih[:, :512], stride 517 (scalar)
        int e = tid + i * 256, r = e >> 9, k2 = e & 511;
        sm->Cw[r * 512 + k2] = W0ih[grow(r) * 517 + k2];
      }
    }
    if (tid < 32) {
      float xv[5];
      if (s == 0) { xv[0]=0.f; xv[1]=0.f; xv[2]=1.f; xv[3]=0.f; xv[4]=0.f; }
      else {
        int lp = slen[tid * 24 + (s - 1)];
        int last = min(max(lp - 1, 0), 47);
        const float* q = sketch + ((tid * 24 + (s - 1)) * 48 + last) * 5;
#pragma unroll
        for (int j = 0; j < 5; ++j) xv[j] = q[j];
      }
#pragma unroll
      for (int j = 0; j < 5; ++j) sm->X[tid][j] = xv[j];
    }
    __syncthreads();
    {
      float acc[32];
#pragma unroll
      for (int i = 0; i < 32; ++i) acc[i] = 0.f;
      DOT8x32(sm->Cw, acc);
      float r;
      REDUCE32(acc, r);
      sm->s0v[my_r][my_b] = r;
    }
    __syncthreads();
    if (tid < 64) {
      float g[4];
#pragma unroll
      for (int gi = 0; gi < 4; ++gi) {
        float xd = 0.f;
#pragma unroll
        for (int j = 0; j < 5; ++j) xd += cwx[gi][j] * sm->X[bb][j];
        g[gi] = sm->s0v[gi*2+uu][bb] + cb0[gi] + xd;
      }
      float c = sigm(g[1]) * o_c0 + sigm(g[0]) * tanhf(g[2]);
      o_c0 = c; o_h0 = sigm(g[3]) * tanhf(c);
      h0T[0 * 16384 + bb * 512 + 2 * w + uu] = o_h0;
    }
    gbar();

    // ================= fused iterations =================
    for (int k = 0; k <= 48; ++k) {
      const bool doL0 = (k < 48), doPrev = (k > 0);
      stageF(h0T + (k & 1) * 16384);             // h0(k)
      if (doL0 && tid < 32) {                    // x_{k+1} = sketch[.., k, :]
        const float* q = sketch + ((tid * 24 + s) * 48 + k) * 5;
#pragma unroll
        for (int j = 0; j < 5; ++j) sm->X[tid][j] = q[j];
      }
      float4 hv4 = make_float4(0.f, 0.f, 0.f, 0.f);  // early out-dot load: h1(k-1)
      if (w < 160 && doPrev && tid < 128)
        hv4 = *(const float4*)(h1T + ((k - 1) & 1) * 16384 + bo * 512 + 4 * tid);
      __syncthreads();

      if (doL0) {                                // W0hh @ h0(k)
        float acc0[32];
#pragma unroll
        for (int i = 0; i < 32; ++i) acc0[i] = 0.f;
        DOT8x32((const float*)sm->A[0], acc0);
        float r0;
        REDUCE32(acc0, r0);
        sm->G0[my_r][my_b] = r0;
      }
      float acc1[32];                            // W1ih @ h0(k) [+ W1hh @ h1(k-1)]
#pragma unroll
      for (int i = 0; i < 32; ++i) acc1[i] = 0.f;
      DOT8x32((const float*)sm->A[1], acc1);
      if (doPrev) {
        __syncthreads();
        stageF(h1T + ((k - 1) & 1) * 16384);
        __syncthreads();
        DOT8x32((const float*)sm->A[2], acc1);
      }
      float r1;
      REDUCE32(acc1, r1);
      sm->G1[my_r][my_b] = r1;

      float part = 0.f;                          // out(k-1) partial
      if (w < 160 && doPrev && tid < 128)
        part = hv4.x*wo4.x + hv4.y*wo4.y + hv4.z*wo4.z + hv4.w*wo4.w;
#pragma unroll
      for (int off = 1; off < 64; off <<= 1) part += __shfl_xor(part, off, 64);
      if ((tid & 63) == 0) sm->outred[tid >> 6] = part;
      __syncthreads();

      if (tid < 64) {
        if (doL0) {                              // L0 cell, t = k+1
          if ((k + 1) <= sm->lens[bb]) {
            float g[4];
#pragma unroll
            for (int gi = 0; gi < 4; ++gi) {
              float xd = 0.f;
#pragma unroll
              for (int j = 0; j < 5; ++j) xd += cwx[gi][j] * sm->X[bb][j];
              g[gi] = sm->G0[gi*2+uu][bb] + sm->s0v[gi*2+uu][bb] + cb0[gi] + xd;
            }
            float c = sigm(g[1]) * o_c0 + sigm(g[0]) * tanhf(g[2]);
            o_c0 = c; o_h0 = sigm(g[3]) * tanhf(c);
          }
          h0T[((k + 1) & 1) * 16384 + bb * 512 + 2 * w + uu] = o_h0;
        }
        {                                        // L1 cell, t = k
          if (k <= sm->lens[bb]) {
            float g[4];
#pragma unroll
            for (int gi = 0; gi < 4; ++gi) g[gi] = sm->G1[gi*2+uu][bb] + cb1[gi];
            float c = sigm(g[1]) * o_c1 + sigm(g[0]) * tanhf(g[2]);
            o_c1 = c; o_h1 = sigm(g[3]) * tanhf(c);
          }
          h1T[(k & 1) * 16384 + bb * 512 + 2 * w + uu] = o_h1;
        }
      }
      if (w < 160 && doPrev && tid == 0) {
        float dv = sm->outred[0] + sm->outred[1];
        int tt = k - 1;
        float val = 0.f;
        if (tt < sm->Lmax) val = (tt > sm->lens[bo]) ? bor : (dv + bor);
        out[((bo * 24 + s) * 48 + tt) * 5 + oo] = val;
      }
      gbar();
    }
  }
}

extern "C" void kernel_launch(void* const* d_in, const int* in_sizes, int n_in,
                              void* d_out, int out_size, void* d_ws, size_t ws_size,
                              hipStream_t stream) {
  (void)in_sizes; (void)n_in; (void)out_size; (void)ws_size;
  hipFuncSetAttribute((const void*)rnn_decoder_kernel,
                      hipFuncAttributeMaxDynamicSharedMemorySize, (int)sizeof(SMem));
  // reset barrier flags + generation word (monotonic barids start fresh each call)
  hipMemsetAsync(d_ws, 0, 33024, stream);
  rnn_decoder_kernel<<<dim3(NB), dim3(NT), sizeof(SMem), stream>>>(
      (const float*)d_in[0],   // enc_features
      (const float*)d_in[1],   // vector_sketch
      (const int*)d_in[3],     // batch_stroke_len
      (const float*)d_in[4],   // W_sc_ih
      (const float*)d_in[5],   // W_sc_hh
      (const float*)d_in[6],   // b_sc
      (const float*)d_in[7],   // W0_ih
      (const float*)d_in[8],   // W0_hh
      (const float*)d_in[9],   // b0
      (const float*)d_in[10],  // W1_ih
      (const float*)d_in[11],  // W1_hh
      (const float*)d_in[12],  // b1
      (const float*)d_in[13],  // W_out
      (const float*)d_in[14],  // b_out
      (float*)d_out, (float*)d_ws);
}

// Round 3
// 28787.747 us; speedup vs baseline: 2.6332x; 2.0213x over previous
//
#include <hip/hip_runtime.h>

#define NB 256
#define NT 256
#define AGT __HIP_MEMORY_SCOPE_AGENT

// B=32, S=24, T=48, hidden 512, gate dim 2048.
// Block w owns hidden units {2w,2w+1}; local gate-row r in [0,8):
// global gate row = (r>>1)*512 + 2w + (r&1).
//
// Cross-block h broadcast + barrier are done ENTIRELY with relaxed
// agent-scope atomics (sc0 sc1 -> served coherently by the LLC, bypassing
// the non-coherent per-XCD L2s). NO agent fences anywhere: fences emit
// buffer_wbl2/buffer_inv L2 walks (the R2 47us/phase cost). Ordering is
// manual: data stores -> s_waitcnt vmcnt(0) -> flag store; poll -> reads.

struct __align__(16) SMem {
  float A[3][8][512];      // persistent W0hh, W1ih, W1hh rows (48KB)
  float Bh[32 * 512];      // staged h tile (64KB)
  float Cw[8 * 512];       // streamed weight rows (16KB)
  float G0[8][32];
  float G1[8][32];
  float e0v[8][32];
  float s0v[8][32];
  float X[32][8];
  float outred[4];
  int   lens[32];
  int   Lmax;
};

__device__ __forceinline__ float sigm(float x) { return 1.0f / (1.0f + expf(-x)); }
__device__ __forceinline__ unsigned long long packf2(float lo, float hi) {
  return (unsigned long long)__float_as_uint(lo) |
         ((unsigned long long)__float_as_uint(hi) << 32);
}
__device__ __forceinline__ float unplo(unsigned long long u) { return __uint_as_float((unsigned)u); }
__device__ __forceinline__ float unphi(unsigned long long u) { return __uint_as_float((unsigned)(u >> 32)); }

#define DOT8x32(WPTR, ACC) do { \
  const float4* B4_ = (const float4*)sm->Bh; \
  const float4* W4_ = (const float4*)(WPTR); \
  _Pragma("unroll") \
  for (int i_ = 0; i_ < 4; ++i_) { \
    const int kf_ = kl + 32 * i_; \
    float4 w0_ = W4_[(rg*4+0)*128 + kf_]; \
    float4 w1_ = W4_[(rg*4+1)*128 + kf_]; \
    float4 w2_ = W4_[(rg*4+2)*128 + kf_]; \
    float4 w3_ = W4_[(rg*4+3)*128 + kf_]; \
    _Pragma("unroll") \
    for (int b_ = 0; b_ < 8; ++b_) { \
      float4 h_ = B4_[(bg*8+b_)*128 + kf_]; \
      ACC[0*8+b_] += w0_.x*h_.x + w0_.y*h_.y + w0_.z*h_.z + w0_.w*h_.w; \
      ACC[1*8+b_] += w1_.x*h_.x + w1_.y*h_.y + w1_.z*h_.z + w1_.w*h_.w; \
      ACC[2*8+b_] += w2_.x*h_.x + w2_.y*h_.y + w2_.z*h_.z + w2_.w*h_.w; \
      ACC[3*8+b_] += w3_.x*h_.x + w3_.y*h_.y + w3_.z*h_.z + w3_.w*h_.w; \
    } \
  } \
} while (0)

#define REDUCE32(ACC, OUTV) do { \
  _Pragma("unroll") \
  for (int lvl_ = 0; lvl_ < 5; ++lvl_) { \
    const int mk_ = 1 << lvl_; \
    const int hc_ = 16 >> lvl_; \
    const bool hi_ = (lane >> lvl_) & 1; \
    _Pragma("unroll") \
    for (int i_ = 0; i_ < hc_; ++i_) { \
      float keep_ = hi_ ? ACC[2*i_+1] : ACC[2*i_]; \
      float send_ = hi_ ? ACC[2*i_]   : ACC[2*i_+1]; \
      ACC[i_] = keep_ + __shfl_xor(send_, mk_, 64); \
    } \
  } \
  OUTV = ACC[0]; \
} while (0)

extern "C" __global__ void __launch_bounds__(NT, 1)
rnn_decoder_kernel(const float* __restrict__ enc, const float* __restrict__ sketch,
                   const int* __restrict__ slen,
                   const float* __restrict__ Wsc_ih, const float* __restrict__ Wsc_hh,
                   const float* __restrict__ bsc,
                   const float* __restrict__ W0ih, const float* __restrict__ W0hh,
                   const float* __restrict__ b0,
                   const float* __restrict__ W1ih, const float* __restrict__ W1hh,
                   const float* __restrict__ b1,
                   const float* __restrict__ Wout, const float* __restrict__ bout,
                   float* __restrict__ out, float* __restrict__ ws)
{
  extern __shared__ char smraw[];
  SMem* sm = (SMem*)smraw;
  const int tid = threadIdx.x;
  const int w = blockIdx.x;
  const int lane = tid & 63;
  const int w4 = tid >> 6;
  const int grp = w4 * 2 + (lane >> 5);
  const int rg = grp & 1;
  const int bg = grp >> 1;
  const int kl = lane & 31;
  const int my_r = rg * 4 + (kl >> 3);
  const int my_b = bg * 8 + (kl & 7);
  const int uu = tid >> 5, bb = tid & 31;

  unsigned* flagsU = (unsigned*)ws;            // flags[w], 4B apart, 1KB total
  float* hbase = ws + 256;                     // data region (1KB offset)
  float* h0T = hbase;                          // [2][32][512]
  float* h1T = hbase + 32768;                  // [2][32][512]
  float* sHg = hbase + 65536;                  // [2][32][512]

  auto grow = [&](int r) { return ((r >> 1) * 512) + 2 * w + (r & 1); };

  unsigned barid = 0;
  auto gbar = [&]() {
    ++barid;
    asm volatile("s_waitcnt vmcnt(0)" ::: "memory");   // my data stores at LLC
    __syncthreads();                                    // all waves' stores done
    if (tid == 0)
      __hip_atomic_store(&flagsU[w], barid, __ATOMIC_RELAXED, AGT);
    const unsigned long long* f8 = (const unsigned long long*)flagsU;
    int ok; int spins = 0;
    do {
      ok = 1;
      if (tid < 64) {
        unsigned long long p0 = __hip_atomic_load(&f8[tid],      __ATOMIC_RELAXED, AGT);
        unsigned long long p1 = __hip_atomic_load(&f8[tid + 64], __ATOMIC_RELAXED, AGT);
        ok = (int)(((unsigned)p0 >= barid) & ((unsigned)(p0 >> 32) >= barid) &
                   ((unsigned)p1 >= barid) & ((unsigned)(p1 >> 32) >= barid));
        if (!ok) __builtin_amdgcn_s_sleep(1);
      }
    } while (!__syncthreads_and(ok) && ++spins < 60000); // bailout: garbage > hang
    asm volatile("" ::: "memory");
  };

  // stage a [32][512] tile from LLC (sc1 reads) into LDS Bh
  auto stageL = [&](const float* srcTile) {
    const unsigned long long* s8 = (const unsigned long long*)srcTile;
    unsigned long long* d8 = (unsigned long long*)sm->Bh;
#pragma unroll
    for (int i = 0; i < 32; ++i)
      d8[tid + i * 256] = __hip_atomic_load(&s8[tid + i * 256], __ATOMIC_RELAXED, AGT);
  };

  // pack (uu=0,uu=1) pair for batch bb and store to LLC; call from if(tid<64)
  auto hstore = [&](float* baseT, int par, float val) {
    float hi = __shfl(val, (tid & 31) + 32, 64);
    if (tid < 32)
      __hip_atomic_store((unsigned long long*)baseT + par * 8192 + tid * 256 + w,
                         packf2(val, hi), __ATOMIC_RELAXED, AGT);
  };

  auto loadCw4 = [&](const float* src, int rowStride, int colOff) {
    float4* C4 = (float4*)sm->Cw;
#pragma unroll
    for (int i = 0; i < 4; ++i) {
      int e = tid + i * 256, r = e >> 7, c = e & 127;
      C4[r * 128 + c] = *(const float4*)(src + grow(r) * rowStride + colOff + 4 * c);
    }
  };

  // ---------------- init ----------------
  {
    const float* srcs[3] = {W0hh, W1ih, W1hh};
#pragma unroll
    for (int m = 0; m < 3; ++m) {
      float4* A4 = (float4*)&sm->A[m][0][0];
#pragma unroll
      for (int i = 0; i < 4; ++i) {
        int e = tid + i * 256, r = e >> 7, c = e & 127;
        A4[r * 128 + c] = *(const float4*)(srcs[m] + grow(r) * 512 + 4 * c);
      }
    }
  }
  float cb0[4] = {0,0,0,0}, cb1[4] = {0,0,0,0}, cbsc[4] = {0,0,0,0};
  float cwx[4][5] = {};
  if (tid < 64) {
#pragma unroll
    for (int gi = 0; gi < 4; ++gi) {
      int gr = grow(gi * 2 + uu);
      cb0[gi] = b0[gr]; cb1[gi] = b1[gr]; cbsc[gi] = bsc[gr];
#pragma unroll
      for (int j = 0; j < 5; ++j) cwx[gi][j] = W0ih[gr * 517 + 512 + j];
    }
  }
  const int oo = w % 5, bo = w / 5;
  float4 wo4 = make_float4(0.f, 0.f, 0.f, 0.f);
  float bor = 0.f;
  if (w < 160) {
    bor = bout[oo];
    if (tid < 128) wo4 = *(const float4*)(Wout + oo * 512 + 4 * tid);
  }

  // e0v = raw enc @ Wsc_ih[:, :512].T  (block-local)
  stageL(enc);
  loadCw4(Wsc_ih, 1024, 0);
  __syncthreads();
  {
    float acc[32];
#pragma unroll
    for (int i = 0; i < 32; ++i) acc[i] = 0.f;
    DOT8x32(sm->Cw, acc);
    float r; REDUCE32(acc, r);
    sm->e0v[my_r][my_b] = r;
  }

  float o_csc = 0.f, o_c0 = 0.f, o_h0 = 0.f, o_c1 = 0.f, o_h1 = 0.f;

  for (int s = 0; s < 24; ++s) {
    // ================= scene phase =================
    if (tid < 32) sm->lens[tid] = slen[tid * 24 + s];
    __syncthreads();
    if (tid == 0) {
      int L = 0;
      for (int b2 = 0; b2 < 32; ++b2) L = max(L, sm->lens[b2]);
      sm->Lmax = L;
    }
    if (s > 0) {
      stageL(h1T);                               // final h1 (parity 0)
      loadCw4(Wsc_ih, 1024, 512);
      __syncthreads();
      float acc[32];
#pragma unroll
      for (int i = 0; i < 32; ++i) acc[i] = 0.f;
      DOT8x32(sm->Cw, acc);
      __syncthreads();
      stageL(sHg + ((s - 1) & 1) * 16384);
      loadCw4(Wsc_hh, 512, 0);
      __syncthreads();
      DOT8x32(sm->Cw, acc);
      float r; REDUCE32(acc, r);
      sm->G0[my_r][my_b] = r;
    }
    __syncthreads();
    if (tid < 64) {
      float g[4];
#pragma unroll
      for (int gi = 0; gi < 4; ++gi)
        g[gi] = sm->e0v[gi*2+uu][bb] + cbsc[gi] + (s > 0 ? sm->G0[gi*2+uu][bb] : 0.f);
      float c = sigm(g[1]) * o_csc + sigm(g[0]) * tanhf(g[2]);
      float h = sigm(g[3]) * tanhf(c);
      o_csc = c;
      hstore(sHg, s & 1, h);
      o_c0 = o_h0 = o_c1 = o_h1 = 0.f;
    }
    gbar();

    // ================= t0 pre-step: h0(0) =================
    stageL(sHg + (s & 1) * 16384);
    {
#pragma unroll
      for (int i = 0; i < 16; ++i) {             // W0ih[:, :512], stride 517
        int e = tid + i * 256, r = e >> 9, k2 = e & 511;
        sm->Cw[r * 512 + k2] = W0ih[grow(r) * 517 + k2];
      }
    }
    if (tid < 32) {
      float xv[5];
      if (s == 0) { xv[0]=0.f; xv[1]=0.f; xv[2]=1.f; xv[3]=0.f; xv[4]=0.f; }
      else {
        int lp = slen[tid * 24 + (s - 1)];
        int last = min(max(lp - 1, 0), 47);
        const float* q = sketch + ((tid * 24 + (s - 1)) * 48 + last) * 5;
#pragma unroll
        for (int j = 0; j < 5; ++j) xv[j] = q[j];
      }
#pragma unroll
      for (int j = 0; j < 5; ++j) sm->X[tid][j] = xv[j];
    }
    __syncthreads();
    {
      float acc[32];
#pragma unroll
      for (int i = 0; i < 32; ++i) acc[i] = 0.f;
      DOT8x32(sm->Cw, acc);
      float r; REDUCE32(acc, r);
      sm->s0v[my_r][my_b] = r;
    }
    __syncthreads();
    if (tid < 64) {
      float g[4];
#pragma unroll
      for (int gi = 0; gi < 4; ++gi) {
        float xd = 0.f;
#pragma unroll
        for (int j = 0; j < 5; ++j) xd += cwx[gi][j] * sm->X[bb][j];
        g[gi] = sm->s0v[gi*2+uu][bb] + cb0[gi] + xd;
      }
      float c = sigm(g[1]) * o_c0 + sigm(g[0]) * tanhf(g[2]);
      o_c0 = c; o_h0 = sigm(g[3]) * tanhf(c);
      hstore(h0T, 0, o_h0);
    }
    gbar();

    // ================= fused iterations =================
    for (int k = 0; k <= 48; ++k) {
      const bool doL0 = (k < 48), doPrev = (k > 0);
      stageL(h0T + (k & 1) * 16384);             // h0(k)
      if (doL0 && tid < 32) {
        const float* q = sketch + ((tid * 24 + s) * 48 + k) * 5;
#pragma unroll
        for (int j = 0; j < 5; ++j) sm->X[tid][j] = q[j];
      }
      unsigned long long hA = 0ull, hB = 0ull;   // early out-dot load: h1(k-1)
      if (w < 160 && doPrev && tid < 128) {
        const unsigned long long* hp =
            (const unsigned long long*)h1T + ((k - 1) & 1) * 8192 + bo * 256 + 2 * tid;
        hA = __hip_atomic_load(hp,     __ATOMIC_RELAXED, AGT);
        hB = __hip_atomic_load(hp + 1, __ATOMIC_RELAXED, AGT);
      }
      __syncthreads();

      if (doL0) {                                // W0hh @ h0(k)
        float acc0[32];
#pragma unroll
        for (int i = 0; i < 32; ++i) acc0[i] = 0.f;
        DOT8x32((const float*)sm->A[0], acc0);
        float r0; REDUCE32(acc0, r0);
        sm->G0[my_r][my_b] = r0;
      }
      float acc1[32];                            // W1ih @ h0(k) [+ W1hh @ h1(k-1)]
#pragma unroll
      for (int i = 0; i < 32; ++i) acc1[i] = 0.f;
      DOT8x32((const float*)sm->A[1], acc1);
      if (doPrev) {
        __syncthreads();
        stageL(h1T + ((k - 1) & 1) * 16384);
        __syncthreads();
        DOT8x32((const float*)sm->A[2], acc1);
      }
      float r1; REDUCE32(acc1, r1);
      sm->G1[my_r][my_b] = r1;

      float part = 0.f;                          // out(k-1) partial
      if (w < 160 && doPrev && tid < 128)
        part = unplo(hA)*wo4.x + unphi(hA)*wo4.y + unplo(hB)*wo4.z + unphi(hB)*wo4.w;
#pragma unroll
      for (int off = 1; off < 64; off <<= 1) part += __shfl_xor(part, off, 64);
      if ((tid & 63) == 0) sm->outred[tid >> 6] = part;
      __syncthreads();

      if (tid < 64) {
        float nh0 = o_h0, nh1 = o_h1;
        if (doL0) {                              // L0 cell, t = k+1
          if ((k + 1) <= sm->lens[bb]) {
            float g[4];
#pragma unroll
            for (int gi = 0; gi < 4; ++gi) {
              float xd = 0.f;
#pragma unroll
              for (int j = 0; j < 5; ++j) xd += cwx[gi][j] * sm->X[bb][j];
              g[gi] = sm->G0[gi*2+uu][bb] + sm->s0v[gi*2+uu][bb] + cb0[gi] + xd;
            }
            float c = sigm(g[1]) * o_c0 + sigm(g[0]) * tanhf(g[2]);
            o_c0 = c; nh0 = sigm(g[3]) * tanhf(c);
          }
          o_h0 = nh0;
          hstore(h0T, (k + 1) & 1, o_h0);
        }
        {                                        // L1 cell, t = k
          if (k <= sm->lens[bb]) {
            float g[4];
#pragma unroll
            for (int gi = 0; gi < 4; ++gi) g[gi] = sm->G1[gi*2+uu][bb] + cb1[gi];
            float c = sigm(g[1]) * o_c1 + sigm(g[0]) * tanhf(g[2]);
            o_c1 = c; nh1 = sigm(g[3]) * tanhf(c);
          }
          o_h1 = nh1;
          hstore(h1T, k & 1, o_h1);
        }
      }
      if (w < 160 && doPrev && tid == 0) {
        float dv = sm->outred[0] + sm->outred[1];
        int tt = k - 1;
        float val = 0.f;
        if (tt < sm->Lmax) val = (tt > sm->lens[bo]) ? bor : (dv + bor);
        out[((bo * 24 + s) * 48 + tt) * 5 + oo] = val;
      }
      gbar();
    }
  }
}

extern "C" void kernel_launch(void* const* d_in, const int* in_sizes, int n_in,
                              void* d_out, int out_size, void* d_ws, size_t ws_size,
                              hipStream_t stream) {
  (void)in_sizes; (void)n_in; (void)out_size; (void)ws_size;
  hipFuncSetAttribute((const void*)rnn_decoder_kernel,
                      hipFuncAttributeMaxDynamicSharedMemorySize, (int)sizeof(SMem));
  // reset barrier flags (1KB; barids restart each launch/replay)
  hipMemsetAsync(d_ws, 0, 1024, stream);
  rnn_decoder_kernel<<<dim3(NB), dim3(NT), sizeof(SMem), stream>>>(
      (const float*)d_in[0],   // enc_features
      (const float*)d_in[1],   // vector_sketch
      (const int*)d_in[3],     // batch_stroke_len
      (const float*)d_in[4],   // W_sc_ih
      (const float*)d_in[5],   // W_sc_hh
      (const float*)d_in[6],   // b_sc
      (const float*)d_in[7],   // W0_ih
      (const float*)d_in[8],   // W0_hh
      (const float*)d_in[9],   // b0
      (const float*)d_in[10],  // W1_ih
      (const float*)d_in[11],  // W1_hh
      (const float*)d_in[12],  // b1
      (const float*)d_in[13],  // W_out
      (const float*)d_in[14],  // b_out
      (float*)d_out, (float*)d_ws);
}

// Round 4
// 9375.151 us; speedup vs baseline: 8.0857x; 3.0706x over previous
//
#include <hip/hip_runtime.h>

#define NB 64
#define NT 256
#define AGT __HIP_MEMORY_SCOPE_AGENT
typedef unsigned long long ull;
typedef _Float16 f16;
typedef __attribute__((ext_vector_type(8))) _Float16 f16x8;
typedef __attribute__((ext_vector_type(4))) float f32x4;

// B=32, S=24, T=48, hidden 512, gate dim 2048.
// NB=64 blocks; block w owns 8 hidden units {8w..8w+7} of every cell.
// Local gate-row r in [0,32): gate = r>>3, unit = r&7;
// global gate row grow(r) = (r>>3)*512 + 8w + (r&7).
// Recurrent dots via MFMA 16x16x32 f16 (A = weights fp16 in LDS, XOR-swizzled;
// B = h tile fp16 staged in LDS from the LLC exchange buffers).
// Cross-block h exchange: fp16 packed in ull relaxed agent atomics (LLC-coherent),
// NO fences (they emit L2 writeback/invalidate walks - the R2 lesson).

struct __align__(16) SMem {
  unsigned short A[3][32 * 512];   // 96KB: W0hh, W1ih, W1hh fp16 rows (swizzled)
  unsigned short Bh[32 * 512];     // 32KB: staged h tile fp16 (swizzled)
  float G0[32][32];                // L0 recurrent dot (or scene dot)
  float G1[32][32];                // L1 dot
  float s0v[32][32];               // W0ih[:, :512] @ sh2 (per stroke)
  float e0v[32][32];               // Wsc_ih[:, :512] @ enc (per session)
  float X[32][8];                  // x_t (5 used)
  unsigned short H0o[32][8];       // fp16 bits of h0 for packing
  unsigned short H1o[32][8];       // fp16 bits of h1
  int lens[32];
  int Lmax;
};

__device__ __forceinline__ float sigm(float x) { return 1.0f / (1.0f + expf(-x)); }

extern "C" __global__ void __launch_bounds__(NT, 1)
rnn_decoder_kernel(const float* __restrict__ enc, const float* __restrict__ sketch,
                   const int* __restrict__ slen,
                   const float* __restrict__ Wsc_ih, const float* __restrict__ Wsc_hh,
                   const float* __restrict__ bsc,
                   const float* __restrict__ W0ih, const float* __restrict__ W0hh,
                   const float* __restrict__ b0,
                   const float* __restrict__ W1ih, const float* __restrict__ W1hh,
                   const float* __restrict__ b1,
                   const float* __restrict__ Wout, const float* __restrict__ bout,
                   float* __restrict__ out, float* __restrict__ ws)
{
  extern __shared__ char smraw[];
  SMem* sm = (SMem*)smraw;
  const int tid = threadIdx.x;
  const int w = blockIdx.x;
  const int lane = tid & 63;
  const int wq = tid >> 6;            // wave 0..3
  const int mh = wq & 1, nh = wq >> 1; // MFMA quadrant
  const int l15 = lane & 15;
  const int kq = lane >> 4;           // k-quarter 0..3
  const int cu = tid >> 5;            // cell unit 0..7
  const int cb = tid & 31;            // cell batch

  unsigned* flagsU = (unsigned*)ws;               // 64 flags, 4B each
  ull* flags8 = (ull*)ws;
  ull* h0T8 = (ull*)((char*)ws + 1024);           // [2][32][128] ull (fp16 x4)
  ull* h1T8 = h0T8 + 8192;
  ull* sHg8 = h1T8 + 8192;

  auto grow = [&](int r) { return ((r >> 3) << 9) + (w << 3) + (r & 7); };
  auto off = [&](int row, int k) { return (((row << 10) + (k << 1)) ^ ((row & 7) << 4)); };
  auto frag = [&](const unsigned short* base, int row, int k) -> f16x8 {
    return *(const f16x8*)((const char*)base + off(row, k));
  };
  auto pk4 = [](float a, float b, float c, float d) -> ull {
    union { _Float16 h; unsigned short u; } q;
    ull r;
    q.h = (_Float16)a; r = q.u;
    q.h = (_Float16)b; r |= (ull)q.u << 16;
    q.h = (_Float16)c; r |= (ull)q.u << 32;
    q.h = (_Float16)d; r |= (ull)q.u << 48;
    return r;
  };
  auto f16bits = [](float x) -> unsigned short {
    union { _Float16 h; unsigned short u; } q; q.h = (_Float16)x; return q.u;
  };

  unsigned barid = 0;
  auto gbar = [&]() {
    ++barid;
    asm volatile("s_waitcnt vmcnt(0)" ::: "memory");
    __syncthreads();
    if (tid == 0) __hip_atomic_store(&flagsU[w], barid, __ATOMIC_RELAXED, AGT);
    int ok; int spins = 0;
    do {
      ok = 1;
      if (tid < 32) {
        ull p = __hip_atomic_load(&flags8[tid], __ATOMIC_RELAXED, AGT);
        ok = (int)(((unsigned)p >= barid) & ((unsigned)(p >> 32) >= barid));
        if (!ok) __builtin_amdgcn_s_sleep(1);
      }
    } while (!__syncthreads_and(ok) && ++spins < 100000);  // bailout: garbage > hang
    asm volatile("" ::: "memory");
  };

  // stage a fp16 [32][512] tile (ull-packed in ws) into swizzled Bh
  auto stage16 = [&](const ull* t8) {
    ull v[16];
#pragma unroll
    for (int i = 0; i < 16; ++i)
      v[i] = __hip_atomic_load(&t8[tid + i * 256], __ATOMIC_RELAXED, AGT);
#pragma unroll
    for (int i = 0; i < 16; ++i) {
      int e = tid + i * 256; int row = e >> 7, k4 = e & 127;
      *(ull*)((char*)sm->Bh + off(row, k4 * 4)) = v[i];
    }
  };

  // MFMA dot with A from LDS (swizzled fp16)
  auto mfma_lds = [&](const unsigned short* Ab, f32x4& acc) {
#pragma unroll
    for (int st = 0; st < 16; ++st) {
      int kk = st * 32 + kq * 8;
      f16x8 a = frag(Ab, mh * 16 + l15, kk);
      f16x8 b = frag(sm->Bh, nh * 16 + l15, kk);
      acc = __builtin_amdgcn_mfma_f32_16x16x32_f16(a, b, acc, 0, 0, 0);
    }
  };
  // MFMA dot with A streamed fp32 from global (vectorized, stride mult of 4)
  auto mfma_gv = [&](const float* W, int stride, int coloff, f32x4& acc) {
    const float* rp = W + (size_t)grow(mh * 16 + l15) * stride + coloff;
#pragma unroll
    for (int st = 0; st < 16; ++st) {
      int kk = st * 32 + kq * 8;
      float4 u0 = *(const float4*)(rp + kk);
      float4 u1 = *(const float4*)(rp + kk + 4);
      f16x8 a;
      a[0] = (f16)u0.x; a[1] = (f16)u0.y; a[2] = (f16)u0.z; a[3] = (f16)u0.w;
      a[4] = (f16)u1.x; a[5] = (f16)u1.y; a[6] = (f16)u1.z; a[7] = (f16)u1.w;
      f16x8 b = frag(sm->Bh, nh * 16 + l15, kk);
      acc = __builtin_amdgcn_mfma_f32_16x16x32_f16(a, b, acc, 0, 0, 0);
    }
  };
  // scalar-load variant (W0ih row stride 517 breaks float4 alignment)
  auto mfma_gs = [&](const float* W, int stride, f32x4& acc) {
    const float* rp = W + (size_t)grow(mh * 16 + l15) * stride;
#pragma unroll
    for (int st = 0; st < 16; ++st) {
      int kk = st * 32 + kq * 8;
      f16x8 a;
#pragma unroll
      for (int j = 0; j < 8; ++j) a[j] = (f16)rp[kk + j];
      f16x8 b = frag(sm->Bh, nh * 16 + l15, kk);
      acc = __builtin_amdgcn_mfma_f32_16x16x32_f16(a, b, acc, 0, 0, 0);
    }
  };
  auto gwrite = [&](float* G, const f32x4& acc) {
    int col = nh * 16 + l15, r0 = mh * 16 + kq * 4;
#pragma unroll
    for (int i = 0; i < 4; ++i) G[(r0 + i) * 32 + col] = acc[i];
  };

  // ---------------- init: fp16 weights into LDS ----------------
  {
    const float* srcs[3] = {W0hh, W1ih, W1hh};
#pragma unroll
    for (int m = 0; m < 3; ++m) {
      char* Ab = (char*)sm->A[m];
#pragma unroll
      for (int i = 0; i < 16; ++i) {
        int e = tid + i * 256; int row = e >> 7, k4 = e & 127;
        float4 v = *(const float4*)(srcs[m] + (size_t)grow(row) * 512 + k4 * 4);
        *(ull*)(Ab + off(row, k4 * 4)) = pk4(v.x, v.y, v.z, v.w);
      }
    }
  }
  float cb0[4], cb1[4], cbsc[4], cwx[4][5];
#pragma unroll
  for (int gi = 0; gi < 4; ++gi) {
    int gr = grow(gi * 8 + cu);
    cb0[gi] = b0[gr]; cb1[gi] = b1[gr]; cbsc[gi] = bsc[gr];
#pragma unroll
    for (int j = 0; j < 5; ++j) cwx[gi][j] = W0ih[(size_t)gr * 517 + 512 + j];
  }

  // e0v = Wsc_ih[:, :512] @ enc  (enc is fp32 input: convert-stage into Bh)
  {
#pragma unroll
    for (int i = 0; i < 16; ++i) {
      int e = tid + i * 256; int b = e >> 7, k4 = e & 127;
      float4 v = *(const float4*)(enc + b * 512 + k4 * 4);
      *(ull*)((char*)sm->Bh + off(b, k4 * 4)) = pk4(v.x, v.y, v.z, v.w);
    }
    __syncthreads();
    f32x4 acc = {0.f, 0.f, 0.f, 0.f};
    mfma_gv(Wsc_ih, 1024, 0, acc);
    gwrite(&sm->e0v[0][0], acc);
    __syncthreads();
  }

  float o_csc = 0.f, o_c0 = 0.f, o_h0 = 0.f, o_c1 = 0.f, o_h1 = 0.f;

  for (int s = 0; s < 24; ++s) {
    // ================= scene phase =================
    if (tid < 32) sm->lens[tid] = slen[tid * 24 + s];
    __syncthreads();
    if (tid == 0) {
      int L = 0;
      for (int b2 = 0; b2 < 32; ++b2) L = max(L, sm->lens[b2]);
      sm->Lmax = L;
    }
    if (s > 0) {
      f32x4 asc = {0.f, 0.f, 0.f, 0.f};
      stage16(h1T8);                           // final h1 of prev stroke (parity 0)
      __syncthreads();
      mfma_gv(Wsc_ih, 1024, 512, asc);
      __syncthreads();
      stage16(sHg8 + ((s - 1) & 1) * 4096);
      __syncthreads();
      mfma_gv(Wsc_hh, 512, 0, asc);
      gwrite(&sm->G0[0][0], asc);
    }
    __syncthreads();
    {                                          // scene cell (all 256 threads)
      float g[4];
#pragma unroll
      for (int gi = 0; gi < 4; ++gi)
        g[gi] = sm->e0v[gi * 8 + cu][cb] + cbsc[gi] +
                (s > 0 ? sm->G0[gi * 8 + cu][cb] : 0.f);
      float c = sigm(g[1]) * o_csc + sigm(g[0]) * tanhf(g[2]);
      float h = sigm(g[3]) * tanhf(c);
      o_csc = c;
      sm->H0o[cb][cu] = f16bits(h);
      o_c0 = o_h0 = o_c1 = o_h1 = 0.f;
    }
    __syncthreads();
    if (tid < 64) {
      int b2 = tid >> 1, ch = tid & 1;
      ull pv = (ull)sm->H0o[b2][ch * 4] | ((ull)sm->H0o[b2][ch * 4 + 1] << 16) |
               ((ull)sm->H0o[b2][ch * 4 + 2] << 32) | ((ull)sm->H0o[b2][ch * 4 + 3] << 48);
      __hip_atomic_store(&sHg8[(s & 1) * 4096 + b2 * 128 + w * 2 + ch], pv,
                         __ATOMIC_RELAXED, AGT);
    }
    gbar();

    // ================= t0 pre-step: h0(0) =================
    stage16(sHg8 + (s & 1) * 4096);
    if (tid < 32) {
      float xv[5];
      if (s == 0) { xv[0] = 0.f; xv[1] = 0.f; xv[2] = 1.f; xv[3] = 0.f; xv[4] = 0.f; }
      else {
        int lp = slen[tid * 24 + (s - 1)];
        int last = min(max(lp - 1, 0), 47);
        const float* q = sketch + ((tid * 24 + (s - 1)) * 48 + last) * 5;
#pragma unroll
        for (int j = 0; j < 5; ++j) xv[j] = q[j];
      }
#pragma unroll
      for (int j = 0; j < 5; ++j) sm->X[tid][j] = xv[j];
    }
    __syncthreads();
    {
      f32x4 a0v = {0.f, 0.f, 0.f, 0.f};
      mfma_gs(W0ih, 517, a0v);
      gwrite(&sm->s0v[0][0], a0v);
    }
    __syncthreads();
    {                                          // L0 cell t=0 (always valid: lens>=1)
      float g[4];
#pragma unroll
      for (int gi = 0; gi < 4; ++gi) {
        float xd = 0.f;
#pragma unroll
        for (int j = 0; j < 5; ++j) xd += cwx[gi][j] * sm->X[cb][j];
        g[gi] = sm->s0v[gi * 8 + cu][cb] + cb0[gi] + xd;
      }
      float c = sigm(g[1]) * o_c0 + sigm(g[0]) * tanhf(g[2]);
      o_c0 = c; o_h0 = sigm(g[3]) * tanhf(c);
      sm->H0o[cb][cu] = f16bits(o_h0);
    }
    __syncthreads();
    if (tid < 64) {
      int b2 = tid >> 1, ch = tid & 1;
      ull pv = (ull)sm->H0o[b2][ch * 4] | ((ull)sm->H0o[b2][ch * 4 + 1] << 16) |
               ((ull)sm->H0o[b2][ch * 4 + 2] << 32) | ((ull)sm->H0o[b2][ch * 4 + 3] << 48);
      __hip_atomic_store(&h0T8[b2 * 128 + w * 2 + ch], pv, __ATOMIC_RELAXED, AGT);
    }
    gbar();

    // ================= fused iterations =================
    for (int k = 0; k <= 48; ++k) {
      const bool doL0 = (k < 48), doPrev = (k > 0);
      const int par0 = k & 1, par1 = (k - 1) & 1;

      if (doL0 && tid < 32) {                  // x_{k+1} = sketch[.., k, :]
        const float* q = sketch + ((tid * 24 + s) * 48 + k) * 5;
#pragma unroll
        for (int j = 0; j < 5; ++j) sm->X[tid][j] = q[j];
      }
      // issue exchange loads: h1(k-1) first, then h0(k) (stays in flight)
      ull v1[16], v0[16];
      if (doPrev) {
        const ull* t1 = h1T8 + par1 * 4096;
#pragma unroll
        for (int i = 0; i < 16; ++i)
          v1[i] = __hip_atomic_load(&t1[tid + i * 256], __ATOMIC_RELAXED, AGT);
      }
      {
        const ull* t0 = h0T8 + par0 * 4096;
#pragma unroll
        for (int i = 0; i < 16; ++i)
          v0[i] = __hip_atomic_load(&t0[tid + i * 256], __ATOMIC_RELAXED, AGT);
      }

      f32x4 acc0 = {0.f, 0.f, 0.f, 0.f}, acc1 = {0.f, 0.f, 0.f, 0.f};
      if (doPrev) {
#pragma unroll
        for (int i = 0; i < 16; ++i) {
          int e = tid + i * 256; int row = e >> 7, k4 = e & 127;
          *(ull*)((char*)sm->Bh + off(row, k4 * 4)) = v1[i];
        }
      }
      __syncthreads();
      if (doPrev) {
        mfma_lds(sm->A[2], acc1);              // W1hh @ h1(k-1)
        // fused output out(k-1): block w handles pairs p = w + 64*wq (p<160)
        int p = w + 64 * wq;
        if (p < 160) {
          int pb = p / 5, po = p % 5;
          f16x8 hv = frag(sm->Bh, pb, lane * 8);
          float4 u0 = *(const float4*)(Wout + po * 512 + lane * 8);
          float4 u1 = *(const float4*)(Wout + po * 512 + lane * 8 + 4);
          float sd = (float)hv[0] * u0.x + (float)hv[1] * u0.y + (float)hv[2] * u0.z +
                     (float)hv[3] * u0.w + (float)hv[4] * u1.x + (float)hv[5] * u1.y +
                     (float)hv[6] * u1.z + (float)hv[7] * u1.w;
#pragma unroll
          for (int o2 = 1; o2 < 64; o2 <<= 1) sd += __shfl_xor(sd, o2, 64);
          if (lane == 0) {
            int tt = k - 1;
            float val = 0.f;
            if (tt < sm->Lmax) val = (tt > sm->lens[pb]) ? bout[po] : (sd + bout[po]);
            out[((pb * 24 + s) * 48 + tt) * 5 + po] = val;
          }
        }
      }
      __syncthreads();
      {
#pragma unroll
        for (int i = 0; i < 16; ++i) {
          int e = tid + i * 256; int row = e >> 7, k4 = e & 127;
          *(ull*)((char*)sm->Bh + off(row, k4 * 4)) = v0[i];
        }
      }
      __syncthreads();
      if (doL0) mfma_lds(sm->A[0], acc0);      // W0hh @ h0(k)
      mfma_lds(sm->A[1], acc1);                // W1ih @ h0(k)
      if (doL0) gwrite(&sm->G0[0][0], acc0);
      gwrite(&sm->G1[0][0], acc1);
      __syncthreads();

      {                                        // cell math (all 256 threads)
        if (doL0) {                            // L0, t = k+1
          if ((k + 1) <= sm->lens[cb]) {
            float g[4];
#pragma unroll
            for (int gi = 0; gi < 4; ++gi) {
              float xd = 0.f;
#pragma unroll
              for (int j = 0; j < 5; ++j) xd += cwx[gi][j] * sm->X[cb][j];
              g[gi] = sm->G0[gi * 8 + cu][cb] + sm->s0v[gi * 8 + cu][cb] + cb0[gi] + xd;
            }
            float c = sigm(g[1]) * o_c0 + sigm(g[0]) * tanhf(g[2]);
            o_c0 = c; o_h0 = sigm(g[3]) * tanhf(c);
          }
          sm->H0o[cb][cu] = f16bits(o_h0);
        }
        {                                      // L1, t = k
          if (k <= sm->lens[cb]) {
            float g[4];
#pragma unroll
            for (int gi = 0; gi < 4; ++gi) g[gi] = sm->G1[gi * 8 + cu][cb] + cb1[gi];
            float c = sigm(g[1]) * o_c1 + sigm(g[0]) * tanhf(g[2]);
            o_c1 = c; o_h1 = sigm(g[3]) * tanhf(c);
          }
          sm->H1o[cb][cu] = f16bits(o_h1);
        }
      }
      __syncthreads();
      if (tid < 128) {
        int half = tid >> 6, q2 = tid & 63;
        int b2 = q2 >> 1, ch = q2 & 1;
        if (half == 0) {
          if (doL0) {
            ull pv = (ull)sm->H0o[b2][ch * 4] | ((ull)sm->H0o[b2][ch * 4 + 1] << 16) |
                     ((ull)sm->H0o[b2][ch * 4 + 2] << 32) | ((ull)sm->H0o[b2][ch * 4 + 3] << 48);
            __hip_atomic_store(&h0T8[((k + 1) & 1) * 4096 + b2 * 128 + w * 2 + ch], pv,
                               __ATOMIC_RELAXED, AGT);
          }
        } else {
          ull pv = (ull)sm->H1o[b2][ch * 4] | ((ull)sm->H1o[b2][ch * 4 + 1] << 16) |
                   ((ull)sm->H1o[b2][ch * 4 + 2] << 32) | ((ull)sm->H1o[b2][ch * 4 + 3] << 48);
          __hip_atomic_store(&h1T8[par0 * 4096 + b2 * 128 + w * 2 + ch], pv,
                             __ATOMIC_RELAXED, AGT);
        }
      }
      gbar();
    }
  }
}

extern "C" void kernel_launch(void* const* d_in, const int* in_sizes, int n_in,
                              void* d_out, int out_size, void* d_ws, size_t ws_size,
                              hipStream_t stream) {
  (void)in_sizes; (void)n_in; (void)out_size; (void)ws_size;
  hipFuncSetAttribute((const void*)rnn_decoder_kernel,
                      hipFuncAttributeMaxDynamicSharedMemorySize, (int)sizeof(SMem));
  // reset barrier flags (barids restart each launch/replay)
  hipMemsetAsync(d_ws, 0, 1024, stream);
  rnn_decoder_kernel<<<dim3(NB), dim3(NT), sizeof(SMem), stream>>>(
      (const float*)d_in[0],   // enc_features
      (const float*)d_in[1],   // vector_sketch
      (const int*)d_in[3],     // batch_stroke_len
      (const float*)d_in[4],   // W_sc_ih
      (const float*)d_in[5],   // W_sc_hh
      (const float*)d_in[6],   // b_sc
      (const float*)d_in[7],   // W0_ih
      (const float*)d_in[8],   // W0_hh
      (const float*)d_in[9],   // b0
      (const float*)d_in[10],  // W1_ih
      (const float*)d_in[11],  // W1_hh
      (const float*)d_in[12],  // b1
      (const float*)d_in[13],  // W_out
      (const float*)d_in[14],  // b_out
      (float*)d_out, (float*)d_ws);
}

// Round 6
// 5817.702 us; speedup vs baseline: 13.0300x; 1.6115x over previous
//
#include <hip/hip_runtime.h>

#define NB 256
#define NT 256
#define AGT __HIP_MEMORY_SCOPE_AGENT
typedef unsigned long long ull;
typedef _Float16 f16;
typedef __attribute__((ext_vector_type(8))) _Float16 f16x8;
typedef __attribute__((ext_vector_type(4))) float f32x4;
typedef __attribute__((ext_vector_type(4))) unsigned u32x4;

// B=32, S=24, T=48, hidden 512, gate dim 2048.
// 8 teams x 4 batches, teams by blockIdx (team=w>>5, slot=w&31). Slot owns
// units 16*slot..16*slot+15 (64 gate rows/matrix; wave wq = gate wq).
// NO barriers: every exchanged 8B chunk = 4B payload (2 fp16) + 4B seq.
// Consumers retry-load until seq matches the phase id (LLC-coherent sc0 sc1,
// same bits the compiler emits for agent atomics - the R4-proven path).
// Double buffering is safe: entering phase k requires all peers' phase-(k-1)
// stores, which follow their phase-(k-1) reads -> max skew 1 phase.
// Seq schedule per stroke s (base=51s): scene store base+1, t0 store base+2,
// iter-k store base+3+k. Reads: scene: h1T@51s, sHg@51(s-1)+1; t0: sHg@base+1;
// iter k: h0T,h1T @ base+2+k.

struct __align__(16) SMem {
  unsigned short WA[2][64 * 512];  // 128KB: W0hh, W1ih fp16, XOR-swizzled
  unsigned short B0[4 * 520];      // staged tile, padded rows (1040B)
  unsigned short B1[4 * 520];
  float G0[64][4];
  float G1[64][4];
  float e0v[64][4];
  float s0v[64][4];
  float X[4][8];
  unsigned short Hst0[4][16];
  unsigned short Hst1[4][16];
  int sLens[4];
  int sLmax;
};

__device__ __forceinline__ float sigm(float x) { return 1.0f / (1.0f + expf(-x)); }
__device__ __forceinline__ unsigned short f16b(float x) {
  union { _Float16 h; unsigned short u; } q; q.h = (_Float16)x; return q.u;
}
__device__ __forceinline__ ull pk4(float a, float b, float c, float d) {
  union { _Float16 h; unsigned short u; } q;
  ull r; q.h = (_Float16)a; r = q.u; q.h = (_Float16)b; r |= (ull)q.u << 16;
  q.h = (_Float16)c; r |= (ull)q.u << 32; q.h = (_Float16)d; r |= (ull)q.u << 48;
  return r;
}
__device__ __forceinline__ u32x4 ld1x16(const void* p) {
  u32x4 r;
  asm volatile("global_load_dwordx4 %0, %1, off sc0 sc1\ns_waitcnt vmcnt(0)"
               : "=&v"(r) : "v"(p) : "memory");
  return r;
}

extern "C" __global__ void __launch_bounds__(NT, 1)
rnn_decoder_kernel(const float* __restrict__ enc, const float* __restrict__ sketch,
                   const int* __restrict__ slen,
                   const float* __restrict__ Wsc_ih, const float* __restrict__ Wsc_hh,
                   const float* __restrict__ bsc,
                   const float* __restrict__ W0ih, const float* __restrict__ W0hh,
                   const float* __restrict__ b0,
                   const float* __restrict__ W1ih, const float* __restrict__ W1hh,
                   const float* __restrict__ b1,
                   const float* __restrict__ Wout, const float* __restrict__ bout,
                   float* __restrict__ out, float* __restrict__ ws)
{
  extern __shared__ char smraw[];
  SMem* sm = (SMem*)smraw;
  const int tid = threadIdx.x;
  const int w = blockIdx.x;
  const int team = w >> 5, slot = w & 31;
  const int lane = tid & 63;
  const int wq = tid >> 6;             // wave = gate
  const int l15 = lane & 15;
  const int kq = lane >> 4;            // k-quarter
  const int u = tid >> 2, bl = tid & 3;  // cell role (tid<64)

  // team exchange region: 6144 ull per team (h0T 2x1024, h1T 2x1024, sHg 2x1024)
  ull* tb = (ull*)ws + (size_t)team * 6144;
  ull* h0T = tb;
  ull* h1T = tb + 2048;
  ull* sHg = tb + 4096;

  auto grow = [&](int r) { return ((r >> 4) << 9) + slot * 16 + (r & 15); };

  // ---------- LDS helpers ----------
  auto ldsA = [&](const unsigned short* Wm, int st) -> f16x8 {
    int row = wq * 16 + l15;
    int byte = (((row << 9) + st * 32 + kq * 8) << 1) ^ ((row & 7) << 4);
    return *(const f16x8*)((const char*)Wm + byte);
  };
  auto ldsB = [&](const unsigned short* Bt, int st) -> f16x8 {
    return *(const f16x8*)((const char*)Bt + (l15 & 3) * 1040 + (st * 32 + kq * 8) * 2);
  };
  auto gwrite = [&](float (*G)[4], const f32x4& acc) {
    if (l15 < 4) {
      int r0 = wq * 16 + kq * 4;
#pragma unroll
      for (int i = 0; i < 4; ++i) G[r0 + i][l15] = acc[i];
    }
  };
  auto mfma_gv = [&](const float* W, int stride, int coloff, const unsigned short* Bt, f32x4& acc) {
    const float* rp = W + (size_t)grow(wq * 16 + l15) * stride + coloff;
#pragma unroll
    for (int st = 0; st < 16; ++st) {
      const float* q = rp + st * 32 + kq * 8;
      float4 u0 = *(const float4*)q, u1 = *(const float4*)(q + 4);
      f16x8 a;
      a[0] = (f16)u0.x; a[1] = (f16)u0.y; a[2] = (f16)u0.z; a[3] = (f16)u0.w;
      a[4] = (f16)u1.x; a[5] = (f16)u1.y; a[6] = (f16)u1.z; a[7] = (f16)u1.w;
      acc = __builtin_amdgcn_mfma_f32_16x16x32_f16(a, ldsB(Bt, st), acc, 0, 0, 0);
    }
  };
  auto mfma_gs = [&](const float* W, const unsigned short* Bt, f32x4& acc) {
    const float* rp = W + (size_t)grow(wq * 16 + l15) * 517;
#pragma unroll
    for (int st = 0; st < 16; ++st) {
      const float* q = rp + st * 32 + kq * 8;
      f16x8 a;
#pragma unroll
      for (int j = 0; j < 8; ++j) a[j] = (f16)q[j];
      acc = __builtin_amdgcn_mfma_f32_16x16x32_f16(a, ldsB(Bt, st), acc, 0, 0, 0);
    }
  };

  // ---------- seq-embedded chunk staging ----------
  // chunk i (ull) of a 1024-chunk tile: batch=i>>8, unit-pair=i&255;
  // low 4B = 2 fp16 (units 2*(i&255), +1), high 4B = seq.
  auto putB = [&](unsigned short* Bt, int p, const u32x4& v) {
    int bb2 = p >> 7;               // batch (p in [0,512) chunk-pairs)
    int up = (2 * p) & 255;         // first unit-pair index
    *(ull*)((char*)Bt + bb2 * 1040 + up * 4) = (ull)v.x | ((ull)v.z << 32);
  };
  auto stage_one = [&](const ull* s0, unsigned e0) {
    const char* p0 = (const char*)s0 + tid * 16;
    const char* p1 = (const char*)s0 + (tid + 256) * 16;
    u32x4 a, b;
    asm volatile("global_load_dwordx4 %0, %2, off sc0 sc1\n"
                 "global_load_dwordx4 %1, %3, off sc0 sc1\n"
                 "s_waitcnt vmcnt(0)"
                 : "=&v"(a), "=&v"(b) : "v"(p0), "v"(p1) : "memory");
    int spins = 0;
    while (((a.y ^ e0) | (a.w ^ e0) | (b.y ^ e0) | (b.w ^ e0)) != 0) {
      if (++spins > 20000) break;          // bailout: garbage > hang
      if (spins > 4) __builtin_amdgcn_s_sleep(1);
      if ((a.y ^ e0) | (a.w ^ e0)) a = ld1x16(p0);
      if ((b.y ^ e0) | (b.w ^ e0)) b = ld1x16(p1);
    }
    putB(sm->B0, tid, a); putB(sm->B0, tid + 256, b);
  };
  auto stage_two = [&](const ull* s0, unsigned e0, const ull* s1, unsigned e1) {
    const char* p0 = (const char*)s0 + tid * 16;
    const char* p1 = (const char*)s0 + (tid + 256) * 16;
    const char* p2 = (const char*)s1 + tid * 16;
    const char* p3 = (const char*)s1 + (tid + 256) * 16;
    u32x4 a, b, c, d;
    asm volatile("global_load_dwordx4 %0, %4, off sc0 sc1\n"
                 "global_load_dwordx4 %1, %5, off sc0 sc1\n"
                 "global_load_dwordx4 %2, %6, off sc0 sc1\n"
                 "global_load_dwordx4 %3, %7, off sc0 sc1\n"
                 "s_waitcnt vmcnt(0)"
                 : "=&v"(a), "=&v"(b), "=&v"(c), "=&v"(d)
                 : "v"(p0), "v"(p1), "v"(p2), "v"(p3) : "memory");
    int spins = 0;
    while ((((a.y ^ e0) | (a.w ^ e0) | (b.y ^ e0) | (b.w ^ e0)) |
            ((c.y ^ e1) | (c.w ^ e1) | (d.y ^ e1) | (d.w ^ e1))) != 0) {
      if (++spins > 20000) break;
      if (spins > 4) __builtin_amdgcn_s_sleep(1);
      if ((a.y ^ e0) | (a.w ^ e0)) a = ld1x16(p0);
      if ((b.y ^ e0) | (b.w ^ e0)) b = ld1x16(p1);
      if ((c.y ^ e1) | (c.w ^ e1)) c = ld1x16(p2);
      if ((d.y ^ e1) | (d.w ^ e1)) d = ld1x16(p3);
    }
    putB(sm->B0, tid, a); putB(sm->B0, tid + 256, b);
    putB(sm->B1, tid, c); putB(sm->B1, tid + 256, d);
  };

  // ---------- init: LDS weights (W0hh, W1ih), W1hh in registers ----------
  {
    const float* srcs[2] = {W0hh, W1ih};
#pragma unroll
    for (int m = 0; m < 2; ++m) {
      char* Ab = (char*)sm->WA[m];
      for (int i = 0; i < 32; ++i) {
        int e = tid + i * 256; int row = e >> 7, k4 = e & 127;
        float4 v = *(const float4*)(srcs[m] + (size_t)grow(row) * 512 + k4 * 4);
        int byte = (((row << 9) + k4 * 4) << 1) ^ ((row & 7) << 4);
        *(ull*)(Ab + byte) = pk4(v.x, v.y, v.z, v.w);
      }
    }
  }
  f16x8 whh[16];
  {
    const float* rp = W1hh + (size_t)grow(wq * 16 + l15) * 512;
#pragma unroll
    for (int st = 0; st < 16; ++st) {
      const float* q = rp + st * 32 + kq * 8;
      float4 u0 = *(const float4*)q, u1 = *(const float4*)(q + 4);
      f16x8 a;
      a[0] = (f16)u0.x; a[1] = (f16)u0.y; a[2] = (f16)u0.z; a[3] = (f16)u0.w;
      a[4] = (f16)u1.x; a[5] = (f16)u1.y; a[6] = (f16)u1.z; a[7] = (f16)u1.w;
      whh[st] = a;
    }
  }
  float cb0[4], cb1[4], cbsc[4], cwx[4][5];
  if (tid < 64) {
#pragma unroll
    for (int gi = 0; gi < 4; ++gi) {
      int gr = gi * 512 + slot * 16 + u;
      cb0[gi] = b0[gr]; cb1[gi] = b1[gr]; cbsc[gi] = bsc[gr];
#pragma unroll
      for (int j = 0; j < 5; ++j) cwx[gi][j] = W0ih[(size_t)gr * 517 + 512 + j];
    }
  }
  const int b_o = slot / 5, o_o = slot % 5;
  const bool oslot = (slot < 20);
  float wo[8]; float bo_r = 0.f;
  if (oslot && tid < 64) {
    bo_r = bout[o_o];
#pragma unroll
    for (int j = 0; j < 8; ++j) wo[j] = Wout[o_o * 512 + lane * 8 + j];
  }

  // e0v = Wsc_ih[:, :512] @ enc (team batches; block-local, no exchange)
  {
    int b2 = tid >> 6, c8 = tid & 63;
    const float* q = enc + (size_t)(4 * team + b2) * 512 + c8 * 8;
    float4 u0 = *(const float4*)q, u1 = *(const float4*)(q + 4);
    *(ull*)((char*)sm->B0 + b2 * 1040 + c8 * 16) = pk4(u0.x, u0.y, u0.z, u0.w);
    *(ull*)((char*)sm->B0 + b2 * 1040 + c8 * 16 + 8) = pk4(u1.x, u1.y, u1.z, u1.w);
    __syncthreads();
    f32x4 acc = {0.f, 0.f, 0.f, 0.f};
    mfma_gv(Wsc_ih, 1024, 0, sm->B0, acc);
    gwrite(sm->e0v, acc);
    __syncthreads();
  }

  float o_csc = 0.f, o_c0 = 0.f, o_h0 = 0.f, o_c1 = 0.f, o_h1 = 0.f;

  for (int s = 0; s < 24; ++s) {
    const unsigned base = 51u * (unsigned)s;
    // ================= scene phase =================
    {
      int lv = (tid < 32) ? slen[tid * 24 + s] : 0;
      if (tid < 64) {
#pragma unroll
        for (int o2 = 1; o2 < 64; o2 <<= 1) lv = max(lv, __shfl_xor(lv, o2, 64));
        if (tid == 0) sm->sLmax = lv;
      }
      if (tid < 4) sm->sLens[tid] = slen[(4 * team + tid) * 24 + s];
    }
    if (s > 0)
      stage_two(h1T, base, sHg + ((s - 1) & 1) * 1024, base - 50u);
    __syncthreads();
    if (s > 0) {
      f32x4 acc = {0.f, 0.f, 0.f, 0.f};
      mfma_gv(Wsc_ih, 1024, 512, sm->B0, acc);   // prev_tok = final h1
      mfma_gv(Wsc_hh, 512, 0, sm->B1, acc);      // scene_h(s-1)
      gwrite(sm->G0, acc);
    }
    __syncthreads();
    if (tid < 64) {
      float g[4];
#pragma unroll
      for (int gi = 0; gi < 4; ++gi)
        g[gi] = sm->e0v[gi * 16 + u][bl] + cbsc[gi] + (s > 0 ? sm->G0[gi * 16 + u][bl] : 0.f);
      float c = sigm(g[1]) * o_csc + sigm(g[0]) * tanhf(g[2]);
      float h = sigm(g[3]) * tanhf(c);
      o_csc = c;
      sm->Hst0[bl][u] = f16b(h);
      o_c0 = o_h0 = o_c1 = o_h1 = 0.f;
    }
    __syncthreads();
    if (tid < 32) {
      int b2 = tid >> 3, a2 = tid & 7;
      unsigned pay = sm->Hst0[b2][2 * a2] | ((unsigned)sm->Hst0[b2][2 * a2 + 1] << 16);
      __hip_atomic_store(&sHg[(s & 1) * 1024 + b2 * 256 + slot * 8 + a2],
                         (ull)pay | ((ull)(base + 1u) << 32), __ATOMIC_RELAXED, AGT);
    }

    // ================= t0 pre-step: h0(0) =================
    stage_one(sHg + (s & 1) * 1024, base + 1u);
    if (tid < 4) {
      float xv[5];
      if (s == 0) { xv[0] = 0.f; xv[1] = 0.f; xv[2] = 1.f; xv[3] = 0.f; xv[4] = 0.f; }
      else {
        int bgl = 4 * team + tid;
        int lp = slen[bgl * 24 + (s - 1)];
        int last = min(max(lp - 1, 0), 47);
        const float* q = sketch + ((bgl * 24 + (s - 1)) * 48 + last) * 5;
#pragma unroll
        for (int j = 0; j < 5; ++j) xv[j] = q[j];
      }
#pragma unroll
      for (int j = 0; j < 5; ++j) sm->X[tid][j] = xv[j];
    }
    __syncthreads();
    {
      f32x4 acc = {0.f, 0.f, 0.f, 0.f};
      mfma_gs(W0ih, sm->B0, acc);
      gwrite(sm->s0v, acc);
    }
    __syncthreads();
    if (tid < 64) {
      float g[4];
#pragma unroll
      for (int gi = 0; gi < 4; ++gi) {
        float xd = 0.f;
#pragma unroll
        for (int j = 0; j < 5; ++j) xd += cwx[gi][j] * sm->X[bl][j];
        g[gi] = sm->s0v[gi * 16 + u][bl] + cb0[gi] + xd;
      }
      float c = sigm(g[1]) * o_c0 + sigm(g[0]) * tanhf(g[2]);
      o_c0 = c; o_h0 = sigm(g[3]) * tanhf(c);
      sm->Hst0[bl][u] = f16b(o_h0);
    }
    __syncthreads();
    if (tid < 32) {
      int b2 = tid >> 3, a2 = tid & 7;
      unsigned pay = sm->Hst0[b2][2 * a2] | ((unsigned)sm->Hst0[b2][2 * a2 + 1] << 16);
      __hip_atomic_store(&h0T[0 * 1024 + b2 * 256 + slot * 8 + a2],
                         (ull)pay | ((ull)(base + 2u) << 32), __ATOMIC_RELAXED, AGT);
    }

    // ================= fused iterations =================
    for (int k = 0; k <= 48; ++k) {
      const bool doL0 = (k < 48), doPrev = (k > 0);
      const unsigned eSeq = base + 2u + (unsigned)k;
      const unsigned sSeq = eSeq + 1u;
      if (doPrev)
        stage_two(h0T + (k & 1) * 1024, eSeq, h1T + ((k - 1) & 1) * 1024, eSeq);
      else
        stage_one(h0T + (k & 1) * 1024, eSeq);
      if (doL0 && tid < 4) {
        const float* q = sketch + (((4 * team + tid) * 24 + s) * 48 + k) * 5;
#pragma unroll
        for (int j = 0; j < 5; ++j) sm->X[tid][j] = q[j];
      }
      __syncthreads();

      f32x4 a0 = {0.f, 0.f, 0.f, 0.f}, a1 = {0.f, 0.f, 0.f, 0.f}, a2v = {0.f, 0.f, 0.f, 0.f};
#pragma unroll
      for (int st = 0; st < 16; ++st) {
        f16x8 bb = ldsB(sm->B0, st);
        if (doL0) a0 = __builtin_amdgcn_mfma_f32_16x16x32_f16(ldsA(sm->WA[0], st), bb, a0, 0, 0, 0);
        a1 = __builtin_amdgcn_mfma_f32_16x16x32_f16(ldsA(sm->WA[1], st), bb, a1, 0, 0, 0);
        if (doPrev) a2v = __builtin_amdgcn_mfma_f32_16x16x32_f16(whh[st], ldsB(sm->B1, st), a2v, 0, 0, 0);
      }
      if (doL0) gwrite(sm->G0, a0);
      {
        f32x4 t;
#pragma unroll
        for (int i = 0; i < 4; ++i) t[i] = a1[i] + a2v[i];
        gwrite(sm->G1, t);
      }
      // fused output out(k-1) from staged h1(k-1) (B1)
      if (doPrev && oslot && tid < 64) {
        f16x8 hv = *(const f16x8*)((const char*)sm->B1 + b_o * 1040 + lane * 16);
        float sd = 0.f;
#pragma unroll
        for (int j = 0; j < 8; ++j) sd += (float)hv[j] * wo[j];
#pragma unroll
        for (int o2 = 1; o2 < 64; o2 <<= 1) sd += __shfl_xor(sd, o2, 64);
        if (tid == 0) {
          int tt = k - 1;
          float val = 0.f;
          if (tt < sm->sLmax) val = (tt > sm->sLens[b_o]) ? bo_r : (sd + bo_r);
          out[(((4 * team + b_o) * 24 + s) * 48 + tt) * 5 + o_o] = val;
        }
      }
      __syncthreads();

      if (tid < 64) {
        if (doL0) {                              // L0 cell, t = k+1
          if ((k + 1) <= sm->sLens[bl]) {
            float g[4];
#pragma unroll
            for (int gi = 0; gi < 4; ++gi) {
              float xd = 0.f;
#pragma unroll
              for (int j = 0; j < 5; ++j) xd += cwx[gi][j] * sm->X[bl][j];
              g[gi] = sm->G0[gi * 16 + u][bl] + sm->s0v[gi * 16 + u][bl] + cb0[gi] + xd;
            }
            float c = sigm(g[1]) * o_c0 + sigm(g[0]) * tanhf(g[2]);
            o_c0 = c; o_h0 = sigm(g[3]) * tanhf(c);
          }
          sm->Hst0[bl][u] = f16b(o_h0);
        }
        {                                        // L1 cell, t = k
          if (k <= sm->sLens[bl]) {
            float g[4];
#pragma unroll
            for (int gi = 0; gi < 4; ++gi) g[gi] = sm->G1[gi * 16 + u][bl] + cb1[gi];
            float c = sigm(g[1]) * o_c1 + sigm(g[0]) * tanhf(g[2]);
            o_c1 = c; o_h1 = sigm(g[3]) * tanhf(c);
          }
          sm->Hst1[bl][u] = f16b(o_h1);
        }
      }
      __syncthreads();
      if (tid < 64) {
        int cell = tid >> 5, q2 = tid & 31, b2 = q2 >> 3, a2 = q2 & 7;
        if (cell ? true : doL0) {
          const unsigned short* H = cell ? &sm->Hst1[b2][0] : &sm->Hst0[b2][0];
          unsigned pay = H[2 * a2] | ((unsigned)H[2 * a2 + 1] << 16);
          ull* dst = cell ? (h1T + (k & 1) * 1024) : (h0T + ((k + 1) & 1) * 1024);
          __hip_atomic_store(&dst[b2 * 256 + slot * 8 + a2],
                             (ull)pay | ((ull)sSeq << 32), __ATOMIC_RELAXED, AGT);
        }
      }
    }
  }
}

extern "C" void kernel_launch(void* const* d_in, const int* in_sizes, int n_in,
                              void* d_out, int out_size, void* d_ws, size_t ws_size,
                              hipStream_t stream) {
  (void)in_sizes; (void)n_in; (void)out_size; (void)ws_size;
  hipFuncSetAttribute((const void*)rnn_decoder_kernel,
                      hipFuncAttributeMaxDynamicSharedMemorySize, (int)sizeof(SMem));
  // zero all team exchange regions (seq 0 != any expected seq >= 1)
  hipMemsetAsync(d_ws, 0, 8 * 6144 * 8, stream);
  rnn_decoder_kernel<<<dim3(NB), dim3(NT), sizeof(SMem), stream>>>(
      (const float*)d_in[0],   // enc_features
      (const float*)d_in[1],   // vector_sketch
      (const int*)d_in[3],     // batch_stroke_len
      (const float*)d_in[4],   // W_sc_ih
      (const float*)d_in[5],   // W_sc_hh
      (const float*)d_in[6],   // b_sc
      (const float*)d_in[7],   // W0_ih
      (const float*)d_in[8],   // W0_hh
      (const float*)d_in[9],   // b0
      (const float*)d_in[10],  // W1_ih
      (const float*)d_in[11],  // W1_hh
      (const float*)d_in[12],  // b1
      (const float*)d_in[13],  // W_out
      (const float*)d_in[14],  // b_out
      (float*)d_out, (float*)d_ws);
}

// Round 7
// 5207.292 us; speedup vs baseline: 14.5574x; 1.1172x over previous
//
#include <hip/hip_runtime.h>

#define NB 256
#define NT 256
#define AGT __HIP_MEMORY_SCOPE_AGENT
typedef unsigned long long ull;
typedef _Float16 f16;
typedef __attribute__((ext_vector_type(8))) _Float16 f16x8;
typedef __attribute__((ext_vector_type(4))) float f32x4;
typedef __attribute__((ext_vector_type(4))) unsigned u32x4;

// B=32, S=24, T=48, hidden 512, gate dim 2048.
// 8 teams x 4 batches (team=w>>5, slot=w&31). Slot owns units 16s..16s+15.
// GATE-MAJOR row map: local row r -> global gate row (r&3)*512 + slot*16 + (r>>2),
// so MFMA D (row=(lane>>4)*4+i) gives lane all 4 gates of unit wq*4+(lane>>4)
// for batch (lane&3 of col): cell math is per-lane register math in ALL waves,
// no LDS gate matrix, ONE __syncthreads per phase. B tiles double-buffered by
// phase parity pp. Rows padded to 1040B (uniform LDS bank quads, no XOR).
// Exchange: R6-proven seq-embedded 8B chunks (4B fp16x2 payload + 4B seq),
// sc0 sc1 LLC loads with per-chunk retry; stores are relaxed agent atomics.

struct __align__(16) SMem {
  unsigned short WA[2][64 * 520];   // W0hh, W1ih fp16, row stride 1040B
  unsigned short Bt[2][2][4 * 520]; // [pp][0=h0-src,1=h1-src][4 rows x 520]
  float X[2][4][8];                 // x_t, double-buffered by pp
  int sLens[2][4];                  // per stroke parity
  int sLmax[2];
};

__device__ __forceinline__ float sigm(float x) { return 1.0f / (1.0f + expf(-x)); }
__device__ __forceinline__ unsigned short f16b(float x) {
  union { _Float16 h; unsigned short u; } q; q.h = (_Float16)x; return q.u;
}
__device__ __forceinline__ ull pk4(float a, float b, float c, float d) {
  union { _Float16 h; unsigned short u; } q;
  ull r; q.h = (_Float16)a; r = q.u; q.h = (_Float16)b; r |= (ull)q.u << 16;
  q.h = (_Float16)c; r |= (ull)q.u << 32; q.h = (_Float16)d; r |= (ull)q.u << 48;
  return r;
}
__device__ __forceinline__ u32x4 ld1x16(const void* p) {
  u32x4 r;
  asm volatile("global_load_dwordx4 %0, %1, off sc0 sc1\ns_waitcnt vmcnt(0)"
               : "=&v"(r) : "v"(p) : "memory");
  return r;
}

extern "C" __global__ void __launch_bounds__(NT, 1)
rnn_decoder_kernel(const float* __restrict__ enc, const float* __restrict__ sketch,
                   const int* __restrict__ slen,
                   const float* __restrict__ Wsc_ih, const float* __restrict__ Wsc_hh,
                   const float* __restrict__ bsc,
                   const float* __restrict__ W0ih, const float* __restrict__ W0hh,
                   const float* __restrict__ b0,
                   const float* __restrict__ W1ih, const float* __restrict__ W1hh,
                   const float* __restrict__ b1,
                   const float* __restrict__ Wout, const float* __restrict__ bout,
                   float* __restrict__ out, float* __restrict__ ws)
{
  extern __shared__ char smraw[];
  SMem* sm = (SMem*)smraw;
  const int tid = threadIdx.x;
  const int w = blockIdx.x;
  const int team = w >> 5, slot = w & 31;
  const int lane = tid & 63;
  const int wq = tid >> 6;
  const int l15 = lane & 15;
  const int kq = lane >> 4;            // k-quarter AND unit-subindex of D tile
  const int my_b = l15 & 3;            // this lane's batch
  const int my_u = wq * 4 + kq;        // this lane's local unit (0..15)

  ull* tb = (ull*)ws + (size_t)team * 6144;
  ull* h0T = tb;                       // [2 parity][1024] chunks
  ull* h1T = tb + 2048;
  ull* sHg = tb + 4096;

  auto grow = [&](int r) { return ((r & 3) << 9) + slot * 16 + (r >> 2); };

  auto ldsA = [&](int m, int st) -> f16x8 {
    int row = wq * 16 + l15;
    return *(const f16x8*)((const char*)sm->WA[m] + row * 1040 + st * 64 + kq * 16);
  };
  auto ldsB = [&](const unsigned short* Bp, int st) -> f16x8 {
    return *(const f16x8*)((const char*)Bp + my_b * 1040 + st * 64 + kq * 16);
  };
  auto mfma_gv = [&](const float* W, int stride, int coloff, const unsigned short* Bp, f32x4& acc) {
    const float* rp = W + (size_t)grow(wq * 16 + l15) * stride + coloff;
#pragma unroll
    for (int st = 0; st < 16; ++st) {
      const float* q = rp + st * 32 + kq * 8;
      float4 u0 = *(const float4*)q, u1 = *(const float4*)(q + 4);
      f16x8 a;
      a[0] = (f16)u0.x; a[1] = (f16)u0.y; a[2] = (f16)u0.z; a[3] = (f16)u0.w;
      a[4] = (f16)u1.x; a[5] = (f16)u1.y; a[6] = (f16)u1.z; a[7] = (f16)u1.w;
      acc = __builtin_amdgcn_mfma_f32_16x16x32_f16(a, ldsB(Bp, st), acc, 0, 0, 0);
    }
  };
  auto mfma_gs = [&](const float* W, const unsigned short* Bp, f32x4& acc) {
    const float* rp = W + (size_t)grow(wq * 16 + l15) * 517;
#pragma unroll
    for (int st = 0; st < 16; ++st) {
      const float* q = rp + st * 32 + kq * 8;
      f16x8 a;
#pragma unroll
      for (int j = 0; j < 8; ++j) a[j] = (f16)q[j];
      acc = __builtin_amdgcn_mfma_f32_16x16x32_f16(a, ldsB(Bp, st), acc, 0, 0, 0);
    }
  };

  // ---------- seq-embedded staging (R6 protocol) ----------
  auto putB = [&](unsigned short* Bp, int p, const u32x4& v) {
    int bb2 = p >> 7, up = (2 * p) & 255;
    *(ull*)((char*)Bp + bb2 * 1040 + up * 4) = (ull)v.x | ((ull)v.z << 32);
  };
  auto stage_one = [&](const ull* s0, unsigned e0, unsigned short* Bp) {
    const char* p0 = (const char*)s0 + tid * 16;
    const char* p1 = (const char*)s0 + (tid + 256) * 16;
    u32x4 a, b;
    asm volatile("global_load_dwordx4 %0, %2, off sc0 sc1\n"
                 "global_load_dwordx4 %1, %3, off sc0 sc1\n"
                 "s_waitcnt vmcnt(0)"
                 : "=&v"(a), "=&v"(b) : "v"(p0), "v"(p1) : "memory");
    int spins = 0;
    while (((a.y ^ e0) | (a.w ^ e0) | (b.y ^ e0) | (b.w ^ e0)) != 0) {
      if (++spins > 20000) break;          // bailout: garbage > hang
      if (spins > 4) __builtin_amdgcn_s_sleep(1);
      if ((a.y ^ e0) | (a.w ^ e0)) a = ld1x16(p0);
      if ((b.y ^ e0) | (b.w ^ e0)) b = ld1x16(p1);
    }
    putB(Bp, tid, a); putB(Bp, tid + 256, b);
  };
  auto stage_two = [&](const ull* s0, unsigned e0, unsigned short* Bp0,
                       const ull* s1, unsigned e1, unsigned short* Bp1) {
    const char* p0 = (const char*)s0 + tid * 16;
    const char* p1 = (const char*)s0 + (tid + 256) * 16;
    const char* p2 = (const char*)s1 + tid * 16;
    const char* p3 = (const char*)s1 + (tid + 256) * 16;
    u32x4 a, b, c, d;
    asm volatile("global_load_dwordx4 %0, %4, off sc0 sc1\n"
                 "global_load_dwordx4 %1, %5, off sc0 sc1\n"
                 "global_load_dwordx4 %2, %6, off sc0 sc1\n"
                 "global_load_dwordx4 %3, %7, off sc0 sc1\n"
                 "s_waitcnt vmcnt(0)"
                 : "=&v"(a), "=&v"(b), "=&v"(c), "=&v"(d)
                 : "v"(p0), "v"(p1), "v"(p2), "v"(p3) : "memory");
    int spins = 0;
    while ((((a.y ^ e0) | (a.w ^ e0) | (b.y ^ e0) | (b.w ^ e0)) |
            ((c.y ^ e1) | (c.w ^ e1) | (d.y ^ e1) | (d.w ^ e1))) != 0) {
      if (++spins > 20000) break;
      if (spins > 4) __builtin_amdgcn_s_sleep(1);
      if ((a.y ^ e0) | (a.w ^ e0)) a = ld1x16(p0);
      if ((b.y ^ e0) | (b.w ^ e0)) b = ld1x16(p1);
      if ((c.y ^ e1) | (c.w ^ e1)) c = ld1x16(p2);
      if ((d.y ^ e1) | (d.w ^ e1)) d = ld1x16(p3);
    }
    putB(Bp0, tid, a); putB(Bp0, tid + 256, b);
    putB(Bp1, tid, c); putB(Bp1, tid + 256, d);
  };

  // ---------- init: LDS weights (W0hh, W1ih), W1hh in registers ----------
  {
    const float* srcs[2] = {W0hh, W1ih};
#pragma unroll
    for (int m = 0; m < 2; ++m) {
      char* Ab = (char*)sm->WA[m];
      for (int i = 0; i < 32; ++i) {
        int e = tid + i * 256; int row = e >> 7, k4 = e & 127;
        float4 v = *(const float4*)(srcs[m] + (size_t)grow(row) * 512 + 4 * k4);
        *(ull*)(Ab + row * 1040 + k4 * 8) = pk4(v.x, v.y, v.z, v.w);
      }
    }
  }
  f16x8 whh[16];
  {
    const float* rp = W1hh + (size_t)grow(wq * 16 + l15) * 512;
#pragma unroll
    for (int st = 0; st < 16; ++st) {
      const float* q = rp + st * 32 + kq * 8;
      float4 u0 = *(const float4*)q, u1 = *(const float4*)(q + 4);
      f16x8 a;
      a[0] = (f16)u0.x; a[1] = (f16)u0.y; a[2] = (f16)u0.z; a[3] = (f16)u0.w;
      a[4] = (f16)u1.x; a[5] = (f16)u1.y; a[6] = (f16)u1.z; a[7] = (f16)u1.w;
      whh[st] = a;
    }
  }
  // per-lane cell constants: all 4 gates of this lane's unit
  float cb0[4], cb1[4], cbsc[4], cwx[4][5];
  {
    int gu = slot * 16 + my_u;
#pragma unroll
    for (int gi = 0; gi < 4; ++gi) {
      int gr = gi * 512 + gu;
      cb0[gi] = b0[gr]; cb1[gi] = b1[gr]; cbsc[gi] = bsc[gr];
#pragma unroll
      for (int j = 0; j < 5; ++j) cwx[gi][j] = W0ih[(size_t)gr * 517 + 512 + j];
    }
  }
  const int b_o = slot / 5, o_o = slot % 5;
  const bool oslot = (slot < 20);
  float wo[8]; float bo_r = 0.f;
  if (oslot && tid < 64) {
    bo_r = bout[o_o];
#pragma unroll
    for (int j = 0; j < 8; ++j) wo[j] = Wout[o_o * 512 + lane * 8 + j];
  }

  // e0reg = Wsc_ih[:, :512] @ enc  -> per-lane f32x4 (4 gates of my unit)
  f32x4 e0reg = {0.f, 0.f, 0.f, 0.f};
  {
    int b2 = tid >> 6, c8 = tid & 63;
    const float* q = enc + (size_t)(4 * team + b2) * 512 + c8 * 8;
    float4 u0 = *(const float4*)q, u1 = *(const float4*)(q + 4);
    unsigned short* Bp = &sm->Bt[0][0][0];
    *(ull*)((char*)Bp + b2 * 1040 + c8 * 16) = pk4(u0.x, u0.y, u0.z, u0.w);
    *(ull*)((char*)Bp + b2 * 1040 + c8 * 16 + 8) = pk4(u1.x, u1.y, u1.z, u1.w);
    __syncthreads();
    mfma_gv(Wsc_ih, 1024, 0, Bp, e0reg);
  }

  float o_csc = 0.f, o_c0 = 0.f, o_h0 = 0.f, o_c1 = 0.f, o_h1 = 0.f;
  int pp = 0;

  for (int s = 0; s < 24; ++s) {
    const unsigned base = 51u * (unsigned)s;

    // ================= scene phase =================
    pp ^= 1;
    {
      int lv = (tid < 32) ? slen[tid * 24 + s] : 0;
      if (tid < 64) {
#pragma unroll
        for (int o2 = 1; o2 < 64; o2 <<= 1) lv = max(lv, __shfl_xor(lv, o2, 64));
        if (tid == 0) sm->sLmax[s & 1] = lv;
      }
      if (tid < 4) sm->sLens[s & 1][tid] = slen[(4 * team + tid) * 24 + s];
    }
    {
      unsigned short* Bp0 = &sm->Bt[pp][0][0];
      unsigned short* Bp1 = &sm->Bt[pp][1][0];
      if (s > 0)
        stage_two(h1T, base, Bp0, sHg + ((s - 1) & 1) * 1024, base - 50u, Bp1);
      __syncthreads();
      f32x4 asc = {0.f, 0.f, 0.f, 0.f};
      if (s > 0) {
        mfma_gv(Wsc_ih, 1024, 512, Bp0, asc);   // prev_tok = final h1
        mfma_gv(Wsc_hh, 512, 0, Bp1, asc);      // scene_h(s-1)
      }
      float g[4];
#pragma unroll
      for (int gi = 0; gi < 4; ++gi) g[gi] = e0reg[gi] + cbsc[gi] + asc[gi];
      float c = sigm(g[1]) * o_csc + sigm(g[0]) * tanhf(g[2]);
      float h = sigm(g[3]) * tanhf(c);
      o_csc = c;
      o_c0 = o_h0 = o_c1 = o_h1 = 0.f;
      float hhi = __shfl_down(h, 16, 64);
      if (((kq & 1) == 0) && (l15 < 4)) {
        int chunk = my_b * 256 + slot * 8 + wq * 2 + (kq >> 1);
        unsigned pay = (unsigned)f16b(h) | ((unsigned)f16b(hhi) << 16);
        __hip_atomic_store(&sHg[(s & 1) * 1024 + chunk],
                           (ull)pay | ((ull)(base + 1u) << 32), __ATOMIC_RELAXED, AGT);
      }
    }

    // ================= t0 pre-step: h0(0) =================
    pp ^= 1;
    f32x4 s0reg = {0.f, 0.f, 0.f, 0.f};
    {
      unsigned short* Bp0 = &sm->Bt[pp][0][0];
      if (tid < 4) {
        float xv[5];
        if (s == 0) { xv[0] = 0.f; xv[1] = 0.f; xv[2] = 1.f; xv[3] = 0.f; xv[4] = 0.f; }
        else {
          int bgl = 4 * team + tid;
          int lp = slen[bgl * 24 + (s - 1)];
          int last = min(max(lp - 1, 0), 47);
          const float* q = sketch + ((bgl * 24 + (s - 1)) * 48 + last) * 5;
#pragma unroll
          for (int j = 0; j < 5; ++j) xv[j] = q[j];
        }
#pragma unroll
        for (int j = 0; j < 5; ++j) sm->X[pp][tid][j] = xv[j];
      }
      stage_one(sHg + (s & 1) * 1024, base + 1u, Bp0);
      __syncthreads();
      mfma_gs(W0ih, Bp0, s0reg);
      float g[4];
#pragma unroll
      for (int gi = 0; gi < 4; ++gi) {
        float xd = 0.f;
#pragma unroll
        for (int j = 0; j < 5; ++j) xd += cwx[gi][j] * sm->X[pp][my_b][j];
        g[gi] = s0reg[gi] + cb0[gi] + xd;
      }
      float c = sigm(g[1]) * o_c0 + sigm(g[0]) * tanhf(g[2]);
      o_c0 = c; o_h0 = sigm(g[3]) * tanhf(c);
      float hhi = __shfl_down(o_h0, 16, 64);
      if (((kq & 1) == 0) && (l15 < 4)) {
        int chunk = my_b * 256 + slot * 8 + wq * 2 + (kq >> 1);
        unsigned pay = (unsigned)f16b(o_h0) | ((unsigned)f16b(hhi) << 16);
        __hip_atomic_store(&h0T[chunk],
                           (ull)pay | ((ull)(base + 2u) << 32), __ATOMIC_RELAXED, AGT);
      }
    }

    // ================= fused iterations =================
    for (int k = 0; k <= 48; ++k) {
      const bool doL0 = (k < 48), doPrev = (k > 0);
      const unsigned eSeq = base + 2u + (unsigned)k, sSeq = eSeq + 1u;
      pp ^= 1;
      unsigned short* B0p = &sm->Bt[pp][0][0];
      unsigned short* B1p = &sm->Bt[pp][1][0];
      if (doL0 && tid < 4) {
        const float* q = sketch + (((4 * team + tid) * 24 + s) * 48 + k) * 5;
#pragma unroll
        for (int j = 0; j < 5; ++j) sm->X[pp][tid][j] = q[j];
      }
      if (doPrev)
        stage_two(h0T + (k & 1) * 1024, eSeq, B0p,
                  h1T + ((k - 1) & 1) * 1024, eSeq, B1p);
      else
        stage_one(h0T + (k & 1) * 1024, eSeq, B0p);
      __syncthreads();

      f32x4 a0 = {0.f, 0.f, 0.f, 0.f}, a1 = {0.f, 0.f, 0.f, 0.f};
#pragma unroll
      for (int st = 0; st < 16; ++st) {
        f16x8 bb = ldsB(B0p, st);
        if (doL0) a0 = __builtin_amdgcn_mfma_f32_16x16x32_f16(ldsA(0, st), bb, a0, 0, 0, 0);
        a1 = __builtin_amdgcn_mfma_f32_16x16x32_f16(ldsA(1, st), bb, a1, 0, 0, 0);
      }
      if (doPrev) {
#pragma unroll
        for (int st = 0; st < 16; ++st)
          a1 = __builtin_amdgcn_mfma_f32_16x16x32_f16(whh[st], ldsB(B1p, st), a1, 0, 0, 0);
      }

      // per-lane cell math (all waves; lane owns unit my_u, batch my_b)
      const int Lb = sm->sLens[s & 1][my_b];
      if (doL0 && (k + 1) <= Lb) {
        float g[4];
#pragma unroll
        for (int gi = 0; gi < 4; ++gi) {
          float xd = 0.f;
#pragma unroll
          for (int j = 0; j < 5; ++j) xd += cwx[gi][j] * sm->X[pp][my_b][j];
          g[gi] = a0[gi] + s0reg[gi] + cb0[gi] + xd;
        }
        float c = sigm(g[1]) * o_c0 + sigm(g[0]) * tanhf(g[2]);
        o_c0 = c; o_h0 = sigm(g[3]) * tanhf(c);
      }
      if (k <= Lb) {
        float g[4];
#pragma unroll
        for (int gi = 0; gi < 4; ++gi) g[gi] = a1[gi] + cb1[gi];
        float c = sigm(g[1]) * o_c1 + sigm(g[0]) * tanhf(g[2]);
        o_c1 = c; o_h1 = sigm(g[3]) * tanhf(c);
      }
      float hhi0 = __shfl_down(o_h0, 16, 64);
      float hhi1 = __shfl_down(o_h1, 16, 64);
      if (((kq & 1) == 0) && (l15 < 4)) {
        int chunk = my_b * 256 + slot * 8 + wq * 2 + (kq >> 1);
        if (doL0) {
          unsigned p0 = (unsigned)f16b(o_h0) | ((unsigned)f16b(hhi0) << 16);
          __hip_atomic_store(&h0T[((k + 1) & 1) * 1024 + chunk],
                             (ull)p0 | ((ull)sSeq << 32), __ATOMIC_RELAXED, AGT);
        }
        unsigned p1 = (unsigned)f16b(o_h1) | ((unsigned)f16b(hhi1) << 16);
        __hip_atomic_store(&h1T[(k & 1) * 1024 + chunk],
                           (ull)p1 | ((ull)sSeq << 32), __ATOMIC_RELAXED, AGT);
      }

      // out(k-1) AFTER h stores (off the producer critical path)
      if (doPrev && oslot && tid < 64) {
        f16x8 hv = *(const f16x8*)((const char*)B1p + b_o * 1040 + lane * 16);
        float sd = 0.f;
#pragma unroll
        for (int j = 0; j < 8; ++j) sd += (float)hv[j] * wo[j];
#pragma unroll
        for (int o2 = 1; o2 < 64; o2 <<= 1) sd += __shfl_xor(sd, o2, 64);
        if (tid == 0) {
          int tt = k - 1;
          float val = 0.f;
          if (tt < sm->sLmax[s & 1])
            val = (tt > sm->sLens[s & 1][b_o]) ? bo_r : (sd + bo_r);
          out[(((4 * team + b_o) * 24 + s) * 48 + tt) * 5 + o_o] = val;
        }
      }
    }
  }
}

extern "C" void kernel_launch(void* const* d_in, const int* in_sizes, int n_in,
                              void* d_out, int out_size, void* d_ws, size_t ws_size,
                              hipStream_t stream) {
  (void)in_sizes; (void)n_in; (void)out_size; (void)ws_size;
  hipFuncSetAttribute((const void*)rnn_decoder_kernel,
                      hipFuncAttributeMaxDynamicSharedMemorySize, (int)sizeof(SMem));
  // zero all team exchange regions (seq 0 != any expected seq >= 1)
  hipMemsetAsync(d_ws, 0, 8 * 6144 * 8, stream);
  rnn_decoder_kernel<<<dim3(NB), dim3(NT), sizeof(SMem), stream>>>(
      (const float*)d_in[0],   // enc_features
      (const float*)d_in[1],   // vector_sketch
      (const int*)d_in[3],     // batch_stroke_len
      (const float*)d_in[4],   // W_sc_ih
      (const float*)d_in[5],   // W_sc_hh
      (const float*)d_in[6],   // b_sc
      (const float*)d_in[7],   // W0_ih
      (const float*)d_in[8],   // W0_hh
      (const float*)d_in[9],   // b0
      (const float*)d_in[10],  // W1_ih
      (const float*)d_in[11],  // W1_hh
      (const float*)d_in[12],  // b1
      (const float*)d_in[13],  // W_out
      (const float*)d_in[14],  // b_out
      (float*)d_out, (float*)d_ws);
}

// Round 8
// 5129.087 us; speedup vs baseline: 14.7794x; 1.0152x over previous
//
#include <hip/hip_runtime.h>

#define NB 256
#define NT 256
#define AGT __HIP_MEMORY_SCOPE_AGENT
typedef unsigned long long ull;
typedef _Float16 f16;
typedef __attribute__((ext_vector_type(8))) _Float16 f16x8;
typedef __attribute__((ext_vector_type(4))) float f32x4;
typedef __attribute__((ext_vector_type(4))) unsigned u32x4;

// B=32, S=24, T=48, hidden 512, gate dim 2048.
// 8 teams x 4 batches (team=w>>5, slot=w&31). Slot owns units 16s..16s+15.
// GATE-MAJOR row map grow(r) = (r&3)*512 + slot*16 + (r>>2): MFMA D gives each
// lane all 4 gates of unit wq*4+kq for batch l15&3 -> per-lane register cell
// math in ALL waves, one __syncthreads per phase.
// ALL THREE recurrent weight matrices (W0hh, W1ih, W1hh) are held in REGISTERS
// as MFMA A-fragments (48 x f16x8 = 192 VGPR) -> zero A-side LDS traffic.
// B tiles in LDS with 1056B row stride: wave's 16 fragment addresses cover the
// 8 bank-granules exactly 2x (2-way = free). LDS padded to 96KB -> 1 block/CU.
// Exchange: R6-proven seq-embedded 8B chunks (4B fp16x2 + 4B seq) via
// sc0 sc1 LLC loads with per-chunk retry; stores relaxed agent atomics.

#define BSTR 1056   // B-tile row stride in bytes (528 shorts)

struct __align__(16) SMem {
  unsigned short Bt[2][2][4 * 528]; // [pp][0=h0-src,1=h1-src][4 rows x 528]
  float X[2][4][8];                 // x_t, double-buffered by pp
  int sLens[2][4];
  int sLmax[2];
};

__device__ __forceinline__ float sigm(float x) { return 1.0f / (1.0f + expf(-x)); }
__device__ __forceinline__ unsigned short f16b(float x) {
  union { _Float16 h; unsigned short u; } q; q.h = (_Float16)x; return q.u;
}
__device__ __forceinline__ ull pk4(float a, float b, float c, float d) {
  union { _Float16 h; unsigned short u; } q;
  ull r; q.h = (_Float16)a; r = q.u; q.h = (_Float16)b; r |= (ull)q.u << 16;
  q.h = (_Float16)c; r |= (ull)q.u << 32; q.h = (_Float16)d; r |= (ull)q.u << 48;
  return r;
}
__device__ __forceinline__ u32x4 ld1x16(const void* p) {
  u32x4 r;
  asm volatile("global_load_dwordx4 %0, %1, off sc0 sc1\ns_waitcnt vmcnt(0)"
               : "=&v"(r) : "v"(p) : "memory");
  return r;
}

extern "C" __global__ void __launch_bounds__(NT, 1)
rnn_decoder_kernel(const float* __restrict__ enc, const float* __restrict__ sketch,
                   const int* __restrict__ slen,
                   const float* __restrict__ Wsc_ih, const float* __restrict__ Wsc_hh,
                   const float* __restrict__ bsc,
                   const float* __restrict__ W0ih, const float* __restrict__ W0hh,
                   const float* __restrict__ b0,
                   const float* __restrict__ W1ih, const float* __restrict__ W1hh,
                   const float* __restrict__ b1,
                   const float* __restrict__ Wout, const float* __restrict__ bout,
                   float* __restrict__ out, float* __restrict__ ws)
{
  extern __shared__ char smraw[];
  SMem* sm = (SMem*)smraw;
  const int tid = threadIdx.x;
  const int w = blockIdx.x;
  const int team = w >> 5, slot = w & 31;
  const int lane = tid & 63;
  const int wq = tid >> 6;
  const int l15 = lane & 15;
  const int kq = lane >> 4;
  const int my_b = l15 & 3;
  const int my_u = wq * 4 + kq;

  ull* tb = (ull*)ws + (size_t)team * 6144;
  ull* h0T = tb;
  ull* h1T = tb + 2048;
  ull* sHg = tb + 4096;

  auto grow = [&](int r) { return ((r & 3) << 9) + slot * 16 + (r >> 2); };

  auto ldsB = [&](const unsigned short* Bp, int st) -> f16x8 {
    return *(const f16x8*)((const char*)Bp + my_b * BSTR + st * 64 + kq * 16);
  };
  auto mfma_gv = [&](const float* W, int stride, int coloff, const unsigned short* Bp, f32x4& acc) {
    const float* rp = W + (size_t)grow(wq * 16 + l15) * stride + coloff;
#pragma unroll
    for (int st = 0; st < 16; ++st) {
      const float* q = rp + st * 32 + kq * 8;
      float4 u0 = *(const float4*)q, u1 = *(const float4*)(q + 4);
      f16x8 a;
      a[0] = (f16)u0.x; a[1] = (f16)u0.y; a[2] = (f16)u0.z; a[3] = (f16)u0.w;
      a[4] = (f16)u1.x; a[5] = (f16)u1.y; a[6] = (f16)u1.z; a[7] = (f16)u1.w;
      acc = __builtin_amdgcn_mfma_f32_16x16x32_f16(a, ldsB(Bp, st), acc, 0, 0, 0);
    }
  };
  auto mfma_gs = [&](const float* W, const unsigned short* Bp, f32x4& acc) {
    const float* rp = W + (size_t)grow(wq * 16 + l15) * 517;
#pragma unroll
    for (int st = 0; st < 16; ++st) {
      const float* q = rp + st * 32 + kq * 8;
      f16x8 a;
#pragma unroll
      for (int j = 0; j < 8; ++j) a[j] = (f16)q[j];
      acc = __builtin_amdgcn_mfma_f32_16x16x32_f16(a, ldsB(Bp, st), acc, 0, 0, 0);
    }
  };

  // ---------- seq-embedded staging (R6 protocol) ----------
  auto putB = [&](unsigned short* Bp, int p, const u32x4& v) {
    int bb2 = p >> 7, up = (2 * p) & 255;
    *(ull*)((char*)Bp + bb2 * BSTR + up * 4) = (ull)v.x | ((ull)v.z << 32);
  };
  auto stage_one = [&](const ull* s0, unsigned e0, unsigned short* Bp) {
    const char* p0 = (const char*)s0 + tid * 16;
    const char* p1 = (const char*)s0 + (tid + 256) * 16;
    u32x4 a, b;
    asm volatile("global_load_dwordx4 %0, %2, off sc0 sc1\n"
                 "global_load_dwordx4 %1, %3, off sc0 sc1\n"
                 "s_waitcnt vmcnt(0)"
                 : "=&v"(a), "=&v"(b) : "v"(p0), "v"(p1) : "memory");
    int spins = 0;
    while (((a.y ^ e0) | (a.w ^ e0) | (b.y ^ e0) | (b.w ^ e0)) != 0) {
      if (++spins > 20000) break;          // bailout: garbage > hang
      if (spins > 4) __builtin_amdgcn_s_sleep(1);
      if ((a.y ^ e0) | (a.w ^ e0)) a = ld1x16(p0);
      if ((b.y ^ e0) | (b.w ^ e0)) b = ld1x16(p1);
    }
    putB(Bp, tid, a); putB(Bp, tid + 256, b);
  };
  auto stage_two = [&](const ull* s0, unsigned e0, unsigned short* Bp0,
                       const ull* s1, unsigned e1, unsigned short* Bp1) {
    const char* p0 = (const char*)s0 + tid * 16;
    const char* p1 = (const char*)s0 + (tid + 256) * 16;
    const char* p2 = (const char*)s1 + tid * 16;
    const char* p3 = (const char*)s1 + (tid + 256) * 16;
    u32x4 a, b, c, d;
    asm volatile("global_load_dwordx4 %0, %4, off sc0 sc1\n"
                 "global_load_dwordx4 %1, %5, off sc0 sc1\n"
                 "global_load_dwordx4 %2, %6, off sc0 sc1\n"
                 "global_load_dwordx4 %3, %7, off sc0 sc1\n"
                 "s_waitcnt vmcnt(0)"
                 : "=&v"(a), "=&v"(b), "=&v"(c), "=&v"(d)
                 : "v"(p0), "v"(p1), "v"(p2), "v"(p3) : "memory");
    int spins = 0;
    while ((((a.y ^ e0) | (a.w ^ e0) | (b.y ^ e0) | (b.w ^ e0)) |
            ((c.y ^ e1) | (c.w ^ e1) | (d.y ^ e1) | (d.w ^ e1))) != 0) {
      if (++spins > 20000) break;
      if (spins > 4) __builtin_amdgcn_s_sleep(1);
      if ((a.y ^ e0) | (a.w ^ e0)) a = ld1x16(p0);
      if ((b.y ^ e0) | (b.w ^ e0)) b = ld1x16(p1);
      if ((c.y ^ e1) | (c.w ^ e1)) c = ld1x16(p2);
      if ((d.y ^ e1) | (d.w ^ e1)) d = ld1x16(p3);
    }
    putB(Bp0, tid, a); putB(Bp0, tid + 256, b);
    putB(Bp1, tid, c); putB(Bp1, tid + 256, d);
  };

  // ---------- init: ALL recurrent weights into registers ----------
  f16x8 w0hh[16], w1ih[16], whh[16];
  {
    const float* r0 = W0hh + (size_t)grow(wq * 16 + l15) * 512;
    const float* r1 = W1ih + (size_t)grow(wq * 16 + l15) * 512;
    const float* r2 = W1hh + (size_t)grow(wq * 16 + l15) * 512;
#pragma unroll
    for (int st = 0; st < 16; ++st) {
      const int o = st * 32 + kq * 8;
      float4 u0, u1;
      f16x8 a;
      u0 = *(const float4*)(r0 + o); u1 = *(const float4*)(r0 + o + 4);
      a[0] = (f16)u0.x; a[1] = (f16)u0.y; a[2] = (f16)u0.z; a[3] = (f16)u0.w;
      a[4] = (f16)u1.x; a[5] = (f16)u1.y; a[6] = (f16)u1.z; a[7] = (f16)u1.w;
      w0hh[st] = a;
      u0 = *(const float4*)(r1 + o); u1 = *(const float4*)(r1 + o + 4);
      a[0] = (f16)u0.x; a[1] = (f16)u0.y; a[2] = (f16)u0.z; a[3] = (f16)u0.w;
      a[4] = (f16)u1.x; a[5] = (f16)u1.y; a[6] = (f16)u1.z; a[7] = (f16)u1.w;
      w1ih[st] = a;
      u0 = *(const float4*)(r2 + o); u1 = *(const float4*)(r2 + o + 4);
      a[0] = (f16)u0.x; a[1] = (f16)u0.y; a[2] = (f16)u0.z; a[3] = (f16)u0.w;
      a[4] = (f16)u1.x; a[5] = (f16)u1.y; a[6] = (f16)u1.z; a[7] = (f16)u1.w;
      whh[st] = a;
    }
  }
  // per-lane cell constants: all 4 gates of this lane's unit
  float cb0[4], cb1[4], cbsc[4], cwx[4][5];
  {
    int gu = slot * 16 + my_u;
#pragma unroll
    for (int gi = 0; gi < 4; ++gi) {
      int gr = gi * 512 + gu;
      cb0[gi] = b0[gr]; cb1[gi] = b1[gr]; cbsc[gi] = bsc[gr];
#pragma unroll
      for (int j = 0; j < 5; ++j) cwx[gi][j] = W0ih[(size_t)gr * 517 + 512 + j];
    }
  }
  const int b_o = slot / 5, o_o = slot % 5;
  const bool oslot = (slot < 20);
  float wo[8]; float bo_r = 0.f;
  if (oslot && tid < 64) {
    bo_r = bout[o_o];
#pragma unroll
    for (int j = 0; j < 8; ++j) wo[j] = Wout[o_o * 512 + lane * 8 + j];
  }

  // e0reg = Wsc_ih[:, :512] @ enc  -> per-lane f32x4
  f32x4 e0reg = {0.f, 0.f, 0.f, 0.f};
  {
    int b2 = tid >> 6, c8 = tid & 63;
    const float* q = enc + (size_t)(4 * team + b2) * 512 + c8 * 8;
    float4 u0 = *(const float4*)q, u1 = *(const float4*)(q + 4);
    unsigned short* Bp = &sm->Bt[0][0][0];
    *(ull*)((char*)Bp + b2 * BSTR + c8 * 16) = pk4(u0.x, u0.y, u0.z, u0.w);
    *(ull*)((char*)Bp + b2 * BSTR + c8 * 16 + 8) = pk4(u1.x, u1.y, u1.z, u1.w);
    __syncthreads();
    mfma_gv(Wsc_ih, 1024, 0, Bp, e0reg);
  }

  float o_csc = 0.f, o_c0 = 0.f, o_h0 = 0.f, o_c1 = 0.f, o_h1 = 0.f;
  int pp = 0;

  for (int s = 0; s < 24; ++s) {
    const unsigned base = 51u * (unsigned)s;

    // ================= scene phase =================
    pp ^= 1;
    {
      int lv = (tid < 32) ? slen[tid * 24 + s] : 0;
      if (tid < 64) {
#pragma unroll
        for (int o2 = 1; o2 < 64; o2 <<= 1) lv = max(lv, __shfl_xor(lv, o2, 64));
        if (tid == 0) sm->sLmax[s & 1] = lv;
      }
      if (tid < 4) sm->sLens[s & 1][tid] = slen[(4 * team + tid) * 24 + s];
    }
    {
      unsigned short* Bp0 = &sm->Bt[pp][0][0];
      unsigned short* Bp1 = &sm->Bt[pp][1][0];
      if (s > 0)
        stage_two(h1T, base, Bp0, sHg + ((s - 1) & 1) * 1024, base - 50u, Bp1);
      __syncthreads();
      f32x4 asc = {0.f, 0.f, 0.f, 0.f};
      if (s > 0) {
        mfma_gv(Wsc_ih, 1024, 512, Bp0, asc);   // prev_tok = final h1
        mfma_gv(Wsc_hh, 512, 0, Bp1, asc);      // scene_h(s-1)
      }
      float g[4];
#pragma unroll
      for (int gi = 0; gi < 4; ++gi) g[gi] = e0reg[gi] + cbsc[gi] + asc[gi];
      float c = sigm(g[1]) * o_csc + sigm(g[0]) * tanhf(g[2]);
      float h = sigm(g[3]) * tanhf(c);
      o_csc = c;
      o_c0 = o_h0 = o_c1 = o_h1 = 0.f;
      float hhi = __shfl_down(h, 16, 64);
      if (((kq & 1) == 0) && (l15 < 4)) {
        int chunk = my_b * 256 + slot * 8 + wq * 2 + (kq >> 1);
        unsigned pay = (unsigned)f16b(h) | ((unsigned)f16b(hhi) << 16);
        __hip_atomic_store(&sHg[(s & 1) * 1024 + chunk],
                           (ull)pay | ((ull)(base + 1u) << 32), __ATOMIC_RELAXED, AGT);
      }
    }

    // ================= t0 pre-step: h0(0) =================
    pp ^= 1;
    f32x4 s0reg = {0.f, 0.f, 0.f, 0.f};
    {
      unsigned short* Bp0 = &sm->Bt[pp][0][0];
      if (tid < 4) {
        float xv[5];
        if (s == 0) { xv[0] = 0.f; xv[1] = 0.f; xv[2] = 1.f; xv[3] = 0.f; xv[4] = 0.f; }
        else {
          int bgl = 4 * team + tid;
          int lp = slen[bgl * 24 + (s - 1)];
          int last = min(max(lp - 1, 0), 47);
          const float* q = sketch + ((bgl * 24 + (s - 1)) * 48 + last) * 5;
#pragma unroll
          for (int j = 0; j < 5; ++j) xv[j] = q[j];
        }
#pragma unroll
        for (int j = 0; j < 5; ++j) sm->X[pp][tid][j] = xv[j];
      }
      stage_one(sHg + (s & 1) * 1024, base + 1u, Bp0);
      __syncthreads();
      mfma_gs(W0ih, Bp0, s0reg);
      float g[4];
#pragma unroll
      for (int gi = 0; gi < 4; ++gi) {
        float xd = 0.f;
#pragma unroll
        for (int j = 0; j < 5; ++j) xd += cwx[gi][j] * sm->X[pp][my_b][j];
        g[gi] = s0reg[gi] + cb0[gi] + xd;
      }
      float c = sigm(g[1]) * o_c0 + sigm(g[0]) * tanhf(g[2]);
      o_c0 = c; o_h0 = sigm(g[3]) * tanhf(c);
      float hhi = __shfl_down(o_h0, 16, 64);
      if (((kq & 1) == 0) && (l15 < 4)) {
        int chunk = my_b * 256 + slot * 8 + wq * 2 + (kq >> 1);
        unsigned pay = (unsigned)f16b(o_h0) | ((unsigned)f16b(hhi) << 16);
        __hip_atomic_store(&h0T[chunk],
                           (ull)pay | ((ull)(base + 2u) << 32), __ATOMIC_RELAXED, AGT);
      }
    }

    // ================= fused iterations =================
    for (int k = 0; k <= 48; ++k) {
      const bool doL0 = (k < 48), doPrev = (k > 0);
      const unsigned eSeq = base + 2u + (unsigned)k, sSeq = eSeq + 1u;
      pp ^= 1;
      unsigned short* B0p = &sm->Bt[pp][0][0];
      unsigned short* B1p = &sm->Bt[pp][1][0];
      if (doL0 && tid < 4) {
        const float* q = sketch + (((4 * team + tid) * 24 + s) * 48 + k) * 5;
#pragma unroll
        for (int j = 0; j < 5; ++j) sm->X[pp][tid][j] = q[j];
      }
      if (doPrev)
        stage_two(h0T + (k & 1) * 1024, eSeq, B0p,
                  h1T + ((k - 1) & 1) * 1024, eSeq, B1p);
      else
        stage_one(h0T + (k & 1) * 1024, eSeq, B0p);
      __syncthreads();

      f32x4 a0 = {0.f, 0.f, 0.f, 0.f}, a1 = {0.f, 0.f, 0.f, 0.f};
#pragma unroll
      for (int st = 0; st < 16; ++st) {
        f16x8 bb = ldsB(B0p, st);
        if (doL0) a0 = __builtin_amdgcn_mfma_f32_16x16x32_f16(w0hh[st], bb, a0, 0, 0, 0);
        a1 = __builtin_amdgcn_mfma_f32_16x16x32_f16(w1ih[st], bb, a1, 0, 0, 0);
      }
      if (doPrev) {
#pragma unroll
        for (int st = 0; st < 16; ++st)
          a1 = __builtin_amdgcn_mfma_f32_16x16x32_f16(whh[st], ldsB(B1p, st), a1, 0, 0, 0);
      }

      // per-lane cell math
      const int Lb = sm->sLens[s & 1][my_b];
      if (doL0 && (k + 1) <= Lb) {
        float g[4];
#pragma unroll
        for (int gi = 0; gi < 4; ++gi) {
          float xd = 0.f;
#pragma unroll
          for (int j = 0; j < 5; ++j) xd += cwx[gi][j] * sm->X[pp][my_b][j];
          g[gi] = a0[gi] + s0reg[gi] + cb0[gi] + xd;
        }
        float c = sigm(g[1]) * o_c0 + sigm(g[0]) * tanhf(g[2]);
        o_c0 = c; o_h0 = sigm(g[3]) * tanhf(c);
      }
      if (k <= Lb) {
        float g[4];
#pragma unroll
        for (int gi = 0; gi < 4; ++gi) g[gi] = a1[gi] + cb1[gi];
        float c = sigm(g[1]) * o_c1 + sigm(g[0]) * tanhf(g[2]);
        o_c1 = c; o_h1 = sigm(g[3]) * tanhf(c);
      }
      float hhi0 = __shfl_down(o_h0, 16, 64);
      float hhi1 = __shfl_down(o_h1, 16, 64);
      if (((kq & 1) == 0) && (l15 < 4)) {
        int chunk = my_b * 256 + slot * 8 + wq * 2 + (kq >> 1);
        if (doL0) {
          unsigned p0 = (unsigned)f16b(o_h0) | ((unsigned)f16b(hhi0) << 16);
          __hip_atomic_store(&h0T[((k + 1) & 1) * 1024 + chunk],
                             (ull)p0 | ((ull)sSeq << 32), __ATOMIC_RELAXED, AGT);
        }
        unsigned p1 = (unsigned)f16b(o_h1) | ((unsigned)f16b(hhi1) << 16);
        __hip_atomic_store(&h1T[(k & 1) * 1024 + chunk],
                           (ull)p1 | ((ull)sSeq << 32), __ATOMIC_RELAXED, AGT);
      }

      // out(k-1) AFTER h stores (off the producer critical path)
      if (doPrev && oslot && tid < 64) {
        f16x8 hv = *(const f16x8*)((const char*)B1p + b_o * BSTR + lane * 16);
        float sd = 0.f;
#pragma unroll
        for (int j = 0; j < 8; ++j) sd += (float)hv[j] * wo[j];
#pragma unroll
        for (int o2 = 1; o2 < 64; o2 <<= 1) sd += __shfl_xor(sd, o2, 64);
        if (tid == 0) {
          int tt = k - 1;
          float val = 0.f;
          if (tt < sm->sLmax[s & 1])
            val = (tt > sm->sLens[s & 1][b_o]) ? bo_r : (sd + bo_r);
          out[(((4 * team + b_o) * 24 + s) * 48 + tt) * 5 + o_o] = val;
        }
      }
    }
  }
}

extern "C" void kernel_launch(void* const* d_in, const int* in_sizes, int n_in,
                              void* d_out, int out_size, void* d_ws, size_t ws_size,
                              hipStream_t stream) {
  (void)in_sizes; (void)n_in; (void)out_size; (void)ws_size;
  // Pad LDS to 96KB: forces 1 block/CU (2x96KB > 160KB) so the persistent
  // grid maps 1:1 onto the 256 CUs.
  int lds_bytes = 98304;
  hipFuncSetAttribute((const void*)rnn_decoder_kernel,
                      hipFuncAttributeMaxDynamicSharedMemorySize, lds_bytes);
  // zero all team exchange regions (seq 0 != any expected seq >= 1)
  hipMemsetAsync(d_ws, 0, 8 * 6144 * 8, stream);
  rnn_decoder_kernel<<<dim3(NB), dim3(NT), lds_bytes, stream>>>(
      (const float*)d_in[0],   // enc_features
      (const float*)d_in[1],   // vector_sketch
      (const int*)d_in[3],     // batch_stroke_len
      (const float*)d_in[4],   // W_sc_ih
      (const float*)d_in[5],   // W_sc_hh
      (const float*)d_in[6],   // b_sc
      (const float*)d_in[7],   // W0_ih
      (const float*)d_in[8],   // W0_hh
      (const float*)d_in[9],   // b0
      (const float*)d_in[10],  // W1_ih
      (const float*)d_in[11],  // W1_hh
      (const float*)d_in[12],  // b1
      (const float*)d_in[13],  // W_out
      (const float*)d_in[14],  // b_out
      (float*)d_out, (float*)d_ws);
}

// Round 9
// 4062.399 us; speedup vs baseline: 18.6601x; 1.2626x over previous
//
#include <hip/hip_runtime.h>

#define NB 256
#define NT 256
#define AGT __HIP_MEMORY_SCOPE_AGENT
typedef unsigned long long ull;
typedef _Float16 f16;
typedef __attribute__((ext_vector_type(8))) _Float16 f16x8;
typedef __attribute__((ext_vector_type(4))) float f32x4;
typedef __attribute__((ext_vector_type(4))) unsigned u32x4;

// B=32, S=24, T=48, hidden 512, gate dim 2048.
// 8 teams x 4 batches (team=w>>5, slot=w&31). Slot owns units 16s..16s+15.
// GATE-MAJOR row map grow(r) = (r&3)*512 + slot*16 + (r>>2): per-lane register
// cell math in all waves. All 3 recurrent weight matrices in registers as MFMA
// A-fragments. B tiles in LDS, 1056B row stride (2-way = free).
// R9: SPLIT-WAIT PIPELINE - the h0 chain (W0hh@h0 -> h0') and h1 chain
// (W1ih@h0 + W1hh@h1 -> h1') are staged/computed/stored separately:
//   wait B0(h0) -> sync -> a0/a1(B0 part) -> L0 cell -> EARLY h0 store
//   wait B1(h1) -> sync -> a1 += whh@B1   -> L1 cell -> h1 store -> out
// This collapses the phase period to the h1 chain (~RTT + 0.3us) because h0
// data is always already waiting. Exchange: R6-proven seq-embedded 8B chunks
// (4B fp16x2 + 4B seq), sc0 sc1 LLC loads with per-chunk retry (no sleep for
// first 16 rounds); stores relaxed agent atomics.

#define BSTR 1056   // B-tile row stride in bytes (528 shorts)

struct __align__(16) SMem {
  unsigned short Bt[2][2][4 * 528]; // [pp][0=h0-src,1=h1-src][4 rows x 528]
  float X[2][4][8];                 // x_t, double-buffered by pp
  int sLens[2][4];
  int sLmax[2];
};

__device__ __forceinline__ float sigm(float x) { return 1.0f / (1.0f + expf(-x)); }
__device__ __forceinline__ unsigned short f16b(float x) {
  union { _Float16 h; unsigned short u; } q; q.h = (_Float16)x; return q.u;
}
__device__ __forceinline__ ull pk4(float a, float b, float c, float d) {
  union { _Float16 h; unsigned short u; } q;
  ull r; q.h = (_Float16)a; r = q.u; q.h = (_Float16)b; r |= (ull)q.u << 16;
  q.h = (_Float16)c; r |= (ull)q.u << 32; q.h = (_Float16)d; r |= (ull)q.u << 48;
  return r;
}
__device__ __forceinline__ u32x4 ld1x16(const void* p) {
  u32x4 r;
  asm volatile("global_load_dwordx4 %0, %1, off sc0 sc1\ns_waitcnt vmcnt(0)"
               : "=&v"(r) : "v"(p) : "memory");
  return r;
}

extern "C" __global__ void __launch_bounds__(NT, 1)
rnn_decoder_kernel(const float* __restrict__ enc, const float* __restrict__ sketch,
                   const int* __restrict__ slen,
                   const float* __restrict__ Wsc_ih, const float* __restrict__ Wsc_hh,
                   const float* __restrict__ bsc,
                   const float* __restrict__ W0ih, const float* __restrict__ W0hh,
                   const float* __restrict__ b0,
                   const float* __restrict__ W1ih, const float* __restrict__ W1hh,
                   const float* __restrict__ b1,
                   const float* __restrict__ Wout, const float* __restrict__ bout,
                   float* __restrict__ out, float* __restrict__ ws)
{
  extern __shared__ char smraw[];
  SMem* sm = (SMem*)smraw;
  const int tid = threadIdx.x;
  const int w = blockIdx.x;
  const int team = w >> 5, slot = w & 31;
  const int lane = tid & 63;
  const int wq = tid >> 6;
  const int l15 = lane & 15;
  const int kq = lane >> 4;
  const int my_b = l15 & 3;
  const int my_u = wq * 4 + kq;

  ull* tb = (ull*)ws + (size_t)team * 6144;
  ull* h0T = tb;
  ull* h1T = tb + 2048;
  ull* sHg = tb + 4096;

  auto grow = [&](int r) { return ((r & 3) << 9) + slot * 16 + (r >> 2); };

  auto ldsB = [&](const unsigned short* Bp, int st) -> f16x8 {
    return *(const f16x8*)((const char*)Bp + my_b * BSTR + st * 64 + kq * 16);
  };
  auto mfma_gv = [&](const float* W, int stride, int coloff, const unsigned short* Bp, f32x4& acc) {
    const float* rp = W + (size_t)grow(wq * 16 + l15) * stride + coloff;
#pragma unroll
    for (int st = 0; st < 16; ++st) {
      const float* q = rp + st * 32 + kq * 8;
      float4 u0 = *(const float4*)q, u1 = *(const float4*)(q + 4);
      f16x8 a;
      a[0] = (f16)u0.x; a[1] = (f16)u0.y; a[2] = (f16)u0.z; a[3] = (f16)u0.w;
      a[4] = (f16)u1.x; a[5] = (f16)u1.y; a[6] = (f16)u1.z; a[7] = (f16)u1.w;
      acc = __builtin_amdgcn_mfma_f32_16x16x32_f16(a, ldsB(Bp, st), acc, 0, 0, 0);
    }
  };
  auto mfma_gs = [&](const float* W, const unsigned short* Bp, f32x4& acc) {
    const float* rp = W + (size_t)grow(wq * 16 + l15) * 517;
#pragma unroll
    for (int st = 0; st < 16; ++st) {
      const float* q = rp + st * 32 + kq * 8;
      f16x8 a;
#pragma unroll
      for (int j = 0; j < 8; ++j) a[j] = (f16)q[j];
      acc = __builtin_amdgcn_mfma_f32_16x16x32_f16(a, ldsB(Bp, st), acc, 0, 0, 0);
    }
  };

  // ---------- seq-embedded staging (R6 protocol, split per tile) ----------
  auto putB = [&](unsigned short* Bp, int p, const u32x4& v) {
    int bb2 = p >> 7, up = (2 * p) & 255;
    *(ull*)((char*)Bp + bb2 * BSTR + up * 4) = (ull)v.x | ((ull)v.z << 32);
  };
  auto stageT = [&](const ull* s0, unsigned e0, unsigned short* Bp) {
    const char* p0 = (const char*)s0 + tid * 16;
    const char* p1 = (const char*)s0 + (tid + 256) * 16;
    u32x4 a, b;
    asm volatile("global_load_dwordx4 %0, %2, off sc0 sc1\n"
                 "global_load_dwordx4 %1, %3, off sc0 sc1\n"
                 "s_waitcnt vmcnt(0)"
                 : "=&v"(a), "=&v"(b) : "v"(p0), "v"(p1) : "memory");
    int spins = 0;
    while (((a.y ^ e0) | (a.w ^ e0) | (b.y ^ e0) | (b.w ^ e0)) != 0) {
      if (++spins > 20000) break;          // bailout: garbage > hang
      if (spins > 16) __builtin_amdgcn_s_sleep(1);
      if ((a.y ^ e0) | (a.w ^ e0)) a = ld1x16(p0);
      if ((b.y ^ e0) | (b.w ^ e0)) b = ld1x16(p1);
    }
    putB(Bp, tid, a); putB(Bp, tid + 256, b);
  };

  // ---------- init: ALL recurrent weights into registers ----------
  f16x8 w0hh[16], w1ih[16], whh[16];
  {
    const float* r0 = W0hh + (size_t)grow(wq * 16 + l15) * 512;
    const float* r1 = W1ih + (size_t)grow(wq * 16 + l15) * 512;
    const float* r2 = W1hh + (size_t)grow(wq * 16 + l15) * 512;
#pragma unroll
    for (int st = 0; st < 16; ++st) {
      const int o = st * 32 + kq * 8;
      float4 u0, u1;
      f16x8 a;
      u0 = *(const float4*)(r0 + o); u1 = *(const float4*)(r0 + o + 4);
      a[0] = (f16)u0.x; a[1] = (f16)u0.y; a[2] = (f16)u0.z; a[3] = (f16)u0.w;
      a[4] = (f16)u1.x; a[5] = (f16)u1.y; a[6] = (f16)u1.z; a[7] = (f16)u1.w;
      w0hh[st] = a;
      u0 = *(const float4*)(r1 + o); u1 = *(const float4*)(r1 + o + 4);
      a[0] = (f16)u0.x; a[1] = (f16)u0.y; a[2] = (f16)u0.z; a[3] = (f16)u0.w;
      a[4] = (f16)u1.x; a[5] = (f16)u1.y; a[6] = (f16)u1.z; a[7] = (f16)u1.w;
      w1ih[st] = a;
      u0 = *(const float4*)(r2 + o); u1 = *(const float4*)(r2 + o + 4);
      a[0] = (f16)u0.x; a[1] = (f16)u0.y; a[2] = (f16)u0.z; a[3] = (f16)u0.w;
      a[4] = (f16)u1.x; a[5] = (f16)u1.y; a[6] = (f16)u1.z; a[7] = (f16)u1.w;
      whh[st] = a;
    }
  }
  // per-lane cell constants: all 4 gates of this lane's unit
  float cb0[4], cb1[4], cbsc[4], cwx[4][5];
  {
    int gu = slot * 16 + my_u;
#pragma unroll
    for (int gi = 0; gi < 4; ++gi) {
      int gr = gi * 512 + gu;
      cb0[gi] = b0[gr]; cb1[gi] = b1[gr]; cbsc[gi] = bsc[gr];
#pragma unroll
      for (int j = 0; j < 5; ++j) cwx[gi][j] = W0ih[(size_t)gr * 517 + 512 + j];
    }
  }
  const int b_o = slot / 5, o_o = slot % 5;
  const bool oslot = (slot < 20);
  float wo[8]; float bo_r = 0.f;
  if (oslot && tid < 64) {
    bo_r = bout[o_o];
#pragma unroll
    for (int j = 0; j < 8; ++j) wo[j] = Wout[o_o * 512 + lane * 8 + j];
  }

  // e0reg = Wsc_ih[:, :512] @ enc  -> per-lane f32x4
  f32x4 e0reg = {0.f, 0.f, 0.f, 0.f};
  {
    int b2 = tid >> 6, c8 = tid & 63;
    const float* q = enc + (size_t)(4 * team + b2) * 512 + c8 * 8;
    float4 u0 = *(const float4*)q, u1 = *(const float4*)(q + 4);
    unsigned short* Bp = &sm->Bt[0][0][0];
    *(ull*)((char*)Bp + b2 * BSTR + c8 * 16) = pk4(u0.x, u0.y, u0.z, u0.w);
    *(ull*)((char*)Bp + b2 * BSTR + c8 * 16 + 8) = pk4(u1.x, u1.y, u1.z, u1.w);
    __syncthreads();
    mfma_gv(Wsc_ih, 1024, 0, Bp, e0reg);
  }

  float o_csc = 0.f, o_c0 = 0.f, o_h0 = 0.f, o_c1 = 0.f, o_h1 = 0.f;
  int pp = 0;

  for (int s = 0; s < 24; ++s) {
    const unsigned base = 51u * (unsigned)s;

    // ================= scene phase =================
    pp ^= 1;
    {
      int lv = (tid < 32) ? slen[tid * 24 + s] : 0;
      if (tid < 64) {
#pragma unroll
        for (int o2 = 1; o2 < 64; o2 <<= 1) lv = max(lv, __shfl_xor(lv, o2, 64));
        if (tid == 0) sm->sLmax[s & 1] = lv;
      }
      if (tid < 4) sm->sLens[s & 1][tid] = slen[(4 * team + tid) * 24 + s];
    }
    {
      unsigned short* Bp0 = &sm->Bt[pp][0][0];
      unsigned short* Bp1 = &sm->Bt[pp][1][0];
      if (s > 0) {
        stageT(h1T, base, Bp0);
        stageT(sHg + ((s - 1) & 1) * 1024, base - 50u, Bp1);
      }
      __syncthreads();
      f32x4 asc = {0.f, 0.f, 0.f, 0.f};
      if (s > 0) {
        mfma_gv(Wsc_ih, 1024, 512, Bp0, asc);   // prev_tok = final h1
        mfma_gv(Wsc_hh, 512, 0, Bp1, asc);      // scene_h(s-1)
      }
      float g[4];
#pragma unroll
      for (int gi = 0; gi < 4; ++gi) g[gi] = e0reg[gi] + cbsc[gi] + asc[gi];
      float c = sigm(g[1]) * o_csc + sigm(g[0]) * tanhf(g[2]);
      float h = sigm(g[3]) * tanhf(c);
      o_csc = c;
      o_c0 = o_h0 = o_c1 = o_h1 = 0.f;
      float hhi = __shfl_down(h, 16, 64);
      if (((kq & 1) == 0) && (l15 < 4)) {
        int chunk = my_b * 256 + slot * 8 + wq * 2 + (kq >> 1);
        unsigned pay = (unsigned)f16b(h) | ((unsigned)f16b(hhi) << 16);
        __hip_atomic_store(&sHg[(s & 1) * 1024 + chunk],
                           (ull)pay | ((ull)(base + 1u) << 32), __ATOMIC_RELAXED, AGT);
      }
    }

    // ================= t0 pre-step: h0(0) =================
    pp ^= 1;
    f32x4 s0reg = {0.f, 0.f, 0.f, 0.f};
    {
      unsigned short* Bp0 = &sm->Bt[pp][0][0];
      if (tid < 4) {
        float xv[5];
        if (s == 0) { xv[0] = 0.f; xv[1] = 0.f; xv[2] = 1.f; xv[3] = 0.f; xv[4] = 0.f; }
        else {
          int bgl = 4 * team + tid;
          int lp = slen[bgl * 24 + (s - 1)];
          int last = min(max(lp - 1, 0), 47);
          const float* q = sketch + ((bgl * 24 + (s - 1)) * 48 + last) * 5;
#pragma unroll
          for (int j = 0; j < 5; ++j) xv[j] = q[j];
        }
#pragma unroll
        for (int j = 0; j < 5; ++j) sm->X[pp][tid][j] = xv[j];
      }
      stageT(sHg + (s & 1) * 1024, base + 1u, Bp0);
      __syncthreads();
      mfma_gs(W0ih, Bp0, s0reg);
      float g[4];
#pragma unroll
      for (int gi = 0; gi < 4; ++gi) {
        float xd = 0.f;
#pragma unroll
        for (int j = 0; j < 5; ++j) xd += cwx[gi][j] * sm->X[pp][my_b][j];
        g[gi] = s0reg[gi] + cb0[gi] + xd;
      }
      float c = sigm(g[1]) * o_c0 + sigm(g[0]) * tanhf(g[2]);
      o_c0 = c; o_h0 = sigm(g[3]) * tanhf(c);
      float hhi = __shfl_down(o_h0, 16, 64);
      if (((kq & 1) == 0) && (l15 < 4)) {
        int chunk = my_b * 256 + slot * 8 + wq * 2 + (kq >> 1);
        unsigned pay = (unsigned)f16b(o_h0) | ((unsigned)f16b(hhi) << 16);
        __hip_atomic_store(&h0T[chunk],
                           (ull)pay | ((ull)(base + 2u) << 32), __ATOMIC_RELAXED, AGT);
      }
    }

    // ================= fused iterations (split-wait pipeline) =================
    for (int k = 0; k <= 48; ++k) {
      const bool doL0 = (k < 48), doPrev = (k > 0);
      const unsigned eSeq = base + 2u + (unsigned)k, sSeq = eSeq + 1u;
      pp ^= 1;
      unsigned short* B0p = &sm->Bt[pp][0][0];
      unsigned short* B1p = &sm->Bt[pp][1][0];
      if (doL0 && tid < 4) {
        const float* q = sketch + (((4 * team + tid) * 24 + s) * 48 + k) * 5;
#pragma unroll
        for (int j = 0; j < 5; ++j) sm->X[pp][tid][j] = q[j];
      }
      // ---- stage 1: h0 tile, B0-dependent MFMAs, L0 cell, EARLY h0 store ----
      stageT(h0T + (k & 1) * 1024, eSeq, B0p);
      __syncthreads();

      f32x4 a0 = {0.f, 0.f, 0.f, 0.f}, a1 = {0.f, 0.f, 0.f, 0.f};
#pragma unroll
      for (int st = 0; st < 16; ++st) {
        f16x8 bb = ldsB(B0p, st);
        if (doL0) a0 = __builtin_amdgcn_mfma_f32_16x16x32_f16(w0hh[st], bb, a0, 0, 0, 0);
        a1 = __builtin_amdgcn_mfma_f32_16x16x32_f16(w1ih[st], bb, a1, 0, 0, 0);
      }
      const int Lb = sm->sLens[s & 1][my_b];
      if (doL0) {
        if ((k + 1) <= Lb) {
          float g[4];
#pragma unroll
          for (int gi = 0; gi < 4; ++gi) {
            float xd = 0.f;
#pragma unroll
            for (int j = 0; j < 5; ++j) xd += cwx[gi][j] * sm->X[pp][my_b][j];
            g[gi] = a0[gi] + s0reg[gi] + cb0[gi] + xd;
          }
          float c = sigm(g[1]) * o_c0 + sigm(g[0]) * tanhf(g[2]);
          o_c0 = c; o_h0 = sigm(g[3]) * tanhf(c);
        }
        float hhi0 = __shfl_down(o_h0, 16, 64);
        if (((kq & 1) == 0) && (l15 < 4)) {
          int chunk = my_b * 256 + slot * 8 + wq * 2 + (kq >> 1);
          unsigned p0 = (unsigned)f16b(o_h0) | ((unsigned)f16b(hhi0) << 16);
          __hip_atomic_store(&h0T[((k + 1) & 1) * 1024 + chunk],
                             (ull)p0 | ((ull)sSeq << 32), __ATOMIC_RELAXED, AGT);
        }
      }
      // ---- stage 2: h1 tile, remaining MFMAs, L1 cell, h1 store ----
      if (doPrev) {
        stageT(h1T + ((k - 1) & 1) * 1024, eSeq, B1p);
        __syncthreads();
#pragma unroll
        for (int st = 0; st < 16; ++st)
          a1 = __builtin_amdgcn_mfma_f32_16x16x32_f16(whh[st], ldsB(B1p, st), a1, 0, 0, 0);
      }
      if (k <= Lb) {
        float g[4];
#pragma unroll
        for (int gi = 0; gi < 4; ++gi) g[gi] = a1[gi] + cb1[gi];
        float c = sigm(g[1]) * o_c1 + sigm(g[0]) * tanhf(g[2]);
        o_c1 = c; o_h1 = sigm(g[3]) * tanhf(c);
      }
      float hhi1 = __shfl_down(o_h1, 16, 64);
      if (((kq & 1) == 0) && (l15 < 4)) {
        int chunk = my_b * 256 + slot * 8 + wq * 2 + (kq >> 1);
        unsigned p1 = (unsigned)f16b(o_h1) | ((unsigned)f16b(hhi1) << 16);
        __hip_atomic_store(&h1T[(k & 1) * 1024 + chunk],
                           (ull)p1 | ((ull)sSeq << 32), __ATOMIC_RELAXED, AGT);
      }

      // out(k-1) from staged h1(k-1) (B1p), off the producer critical path
      if (doPrev && oslot && tid < 64) {
        f16x8 hv = *(const f16x8*)((const char*)B1p + b_o * BSTR + lane * 16);
        float sd = 0.f;
#pragma unroll
        for (int j = 0; j < 8; ++j) sd += (float)hv[j] * wo[j];
#pragma unroll
        for (int o2 = 1; o2 < 64; o2 <<= 1) sd += __shfl_xor(sd, o2, 64);
        if (tid == 0) {
          int tt = k - 1;
          float val = 0.f;
          if (tt < sm->sLmax[s & 1])
            val = (tt > sm->sLens[s & 1][b_o]) ? bo_r : (sd + bo_r);
          out[(((4 * team + b_o) * 24 + s) * 48 + tt) * 5 + o_o] = val;
        }
      }
    }
  }
}

extern "C" void kernel_launch(void* const* d_in, const int* in_sizes, int n_in,
                              void* d_out, int out_size, void* d_ws, size_t ws_size,
                              hipStream_t stream) {
  (void)in_sizes; (void)n_in; (void)out_size; (void)ws_size;
  // Pad LDS to 96KB: forces 1 block/CU so the persistent grid maps 1:1 to CUs.
  int lds_bytes = 98304;
  hipFuncSetAttribute((const void*)rnn_decoder_kernel,
                      hipFuncAttributeMaxDynamicSharedMemorySize, lds_bytes);
  // zero all team exchange regions (seq 0 != any expected seq >= 1)
  hipMemsetAsync(d_ws, 0, 8 * 6144 * 8, stream);
  rnn_decoder_kernel<<<dim3(NB), dim3(NT), lds_bytes, stream>>>(
      (const float*)d_in[0],   // enc_features
      (const float*)d_in[1],   // vector_sketch
      (const int*)d_in[3],     // batch_stroke_len
      (const float*)d_in[4],   // W_sc_ih
      (const float*)d_in[5],   // W_sc_hh
      (const float*)d_in[6],   // b_sc
      (const float*)d_in[7],   // W0_ih
      (const float*)d_in[8],   // W0_hh
      (const float*)d_in[9],   // b0
      (const float*)d_in[10],  // W1_ih
      (const float*)d_in[11],  // W1_hh
      (const float*)d_in[12],  // b1
      (const float*)d_in[13],  // W_out
      (const float*)d_in[14],  // b_out
      (float*)d_out, (float*)d_ws);
}